// Round 15
// baseline (1153.936 us; speedup 1.0000x reference)
//
#include <hip/hip_runtime.h>
#include <hip/hip_bf16.h>
#include <cstdint>
#include <cstddef>
#include <type_traits>

// KAN GLU expert: h = kan(x;w1) * kan(x;w2); out = kan(h;w3)
// kan(x;W) == [silu(x_i), B0..B7(x_i)]_i @ [base_w | spline_w]^T
// -> bf16 MFMA GEMMs with K expanded 9x.
//
// GEMM (R15): 256x256 block, 4 waves (2Mx2N), wave tile 128x128 (acc 256
// VGPR, 1 wave/SIMD), BK=64, ring-2 LDS slots of 64KB, 16x16x32 MFMA.
// Same proven sync skeleton as R12: stage T+1 at T's start, ONE
// vmcnt(0)+lgkm+barrier per K-step. LDS reads drop 192->128KB per K-step
// (wave tile perimeter/area), writes unchanged -> less LDS-BW pressure.
// 128B LDS rows; swizzle gp = gl ^ (row&7) via pre-swizzled global source;
// per-lane read pattern identical to measured-conflict-free R10/R12.
// Fused path: GEMM1 epilogue does GLU (interleaved W12 rows, shfl_xor)
// + KAN features -> A3 directly (no H). GEMM2 single dispatch split-K=4.

#define D_MODEL 1024
#define D_FF    4096
#define NTOK    4096
#define NC      9
#define K1      (D_MODEL * NC)  // 9216
#define K3      (D_FF * NC)     // 36864
#define SPLITK2 16              // fallback chunked GEMM2
#define SPLITKF 4               // fused full GEMM2
#define CHUNK   1024
#define SLOT    65536           // ring-2 slot: A 32KB + B 32KB

typedef __attribute__((ext_vector_type(8))) short bf16x8;
typedef __attribute__((ext_vector_type(4))) float f32x4;

__device__ __forceinline__ unsigned short bf16b(float f) {
  __hip_bfloat16 h = __float2bfloat16(f);
  return __builtin_bit_cast(unsigned short, h);
}

// ---------------------------------------------------------------------------
// silu + 8 cubic B-spline bases on uniform grid t_m = 0.4*m - 2.2
// ---------------------------------------------------------------------------
__device__ __forceinline__ void kan_feat_u(float x, unsigned short* dst) {
  float s = x / (1.0f + __expf(-x));
  float B[11];
#pragma unroll
  for (int j = 0; j < 11; ++j) {
    float gj = -2.2f + 0.4f * j;
    B[j] = (x >= gj && x < gj + 0.4f) ? 1.0f : 0.0f;
  }
#pragma unroll
  for (int p = 1; p <= 3; ++p) {
    float inv = 1.0f / (0.4f * p);
#pragma unroll
    for (int i = 0; i + p < 11; ++i) {
      float gi = -2.2f + 0.4f * i;
      B[i] = (x - gi) * inv * B[i] + ((gi + 0.4f + 0.4f * p) - x) * inv * B[i + 1];
    }
  }
  dst[0] = bf16b(s);
#pragma unroll
  for (int c = 0; c < 8; ++c) dst[1 + c] = bf16b(B[c]);
}

// ---------------------------------------------------------------------------
// Pack two adjacent input-features per thread -> 9 dword stores.
// dst row = o*rowMul + rowBase (rowMul=2 interleaves two layers).
// ---------------------------------------------------------------------------
__global__ void pack_kan_w(const float* __restrict__ bw, const float* __restrict__ sw,
                           __hip_bfloat16* __restrict__ W, int K, int inShift,
                           int rowMul, int rowBase, size_t totalPairs) {
  size_t t = (size_t)blockIdx.x * blockDim.x + threadIdx.x;
  if (t >= totalPairs) return;
  size_t o = t >> (inShift - 1);
  size_t ip = (t & (((size_t)1 << (inShift - 1)) - 1)) * 2;
  size_t e0 = (o << inShift) + ip;
  float2 b = *(const float2*)(bw + e0);
  const float4* sp = (const float4*)(sw + e0 * 8);
  float4 s0 = sp[0], s1 = sp[1], s2 = sp[2], s3 = sp[3];
  unsigned short h[18];
  h[0] = bf16b(b.x);
  h[1] = bf16b(s0.x); h[2] = bf16b(s0.y); h[3] = bf16b(s0.z); h[4] = bf16b(s0.w);
  h[5] = bf16b(s1.x); h[6] = bf16b(s1.y); h[7] = bf16b(s1.z); h[8] = bf16b(s1.w);
  h[9] = bf16b(b.y);
  h[10] = bf16b(s2.x); h[11] = bf16b(s2.y); h[12] = bf16b(s2.z); h[13] = bf16b(s2.w);
  h[14] = bf16b(s3.x); h[15] = bf16b(s3.y); h[16] = bf16b(s3.z); h[17] = bf16b(s3.w);
  uint32_t* dst = (uint32_t*)(W + (o * rowMul + rowBase) * (size_t)K + ip * NC);
#pragma unroll
  for (int k = 0; k < 9; ++k) dst[k] = (uint32_t)h[2 * k] | ((uint32_t)h[2 * k + 1] << 16);
}

// A1 from x; two elements per thread
__global__ void build_a1(const float* __restrict__ x, __hip_bfloat16* __restrict__ A1) {
  size_t t = (size_t)blockIdx.x * blockDim.x + threadIdx.x;
  if (t >= (size_t)NTOK * D_MODEL / 2) return;
  size_t n = t >> 9;
  size_t ip = (t & 511) * 2;
  float2 xv = *(const float2*)(x + n * D_MODEL + ip);
  unsigned short h[18];
  kan_feat_u(xv.x, h);
  kan_feat_u(xv.y, h + 9);
  uint32_t* dst = (uint32_t*)(A1 + n * (size_t)K1 + ip * NC);
#pragma unroll
  for (int k = 0; k < 9; ++k) dst[k] = (uint32_t)h[2 * k] | ((uint32_t)h[2 * k + 1] << 16);
}

// fallback only: h = Hc[:, :4096] * Hc[:, 4096:]; two j per thread
template <typename HT>
__global__ void glu_a3(const HT* __restrict__ Hc, __hip_bfloat16* __restrict__ A3c) {
  size_t t = (size_t)blockIdx.x * blockDim.x + threadIdx.x;
  if (t >= (size_t)CHUNK * D_FF / 2) return;
  size_t n = t >> 11;
  size_t jp = (t & 2047) * 2;
  float a0, a1, c0, c1;
  if constexpr (std::is_same<HT, float>::value) {
    float2 u = *(const float2*)(Hc + n * 8192 + jp);
    float2 v = *(const float2*)(Hc + n * 8192 + 4096 + jp);
    a0 = u.x; a1 = u.y; c0 = v.x; c1 = v.y;
  } else {
    a0 = __bfloat162float(Hc[n * 8192 + jp]);
    a1 = __bfloat162float(Hc[n * 8192 + jp + 1]);
    c0 = __bfloat162float(Hc[n * 8192 + 4096 + jp]);
    c1 = __bfloat162float(Hc[n * 8192 + 4096 + jp + 1]);
  }
  unsigned short h[18];
  kan_feat_u(a0 * c0, h);
  kan_feat_u(a1 * c1, h + 9);
  uint32_t* dst = (uint32_t*)(A3c + n * (size_t)K3 + jp * NC);
#pragma unroll
  for (int k = 0; k < 9; ++k) dst[k] = (uint32_t)h[2 * k] | ((uint32_t)h[2 * k + 1] << 16);
}

// ---------------------------------------------------------------------------
// 256x256 bf16 GEMM, BK=64, ring-2, 4 waves of 128x128. 256 threads.
// Staging per tile: 16 sites x (256thr x 16B) = 64KB. Site = 32 rows x 128B.
// Per-thread: row_in_site = tid>>3, source k-group (tid&7)^((tid>>3)&7);
// LDS dest linear (site*4096 + tid*16) => physical gp = gl ^ (row&7).
// ---------------------------------------------------------------------------
#define STAGE(Ts)                                                                        \
  {                                                                                      \
    const int _sl = ((Ts) & 1) * SLOT;                                                   \
    const size_t _ko = (size_t)(Ts) * 128;                                               \
    _Pragma("unroll") for (int _st = 0; _st < 8; ++_st) {                                \
      __builtin_amdgcn_global_load_lds(                                                  \
          (const __attribute__((address_space(1))) void*)(gA0 + _st * strideS + _ko),    \
          (__attribute__((address_space(3))) void*)(lds_raw + _sl + _st * 4096 + dT),    \
          16, 0, 0);                                                                     \
      __builtin_amdgcn_global_load_lds(                                                  \
          (const __attribute__((address_space(1))) void*)(gB0 + _st * strideS + _ko),    \
          (__attribute__((address_space(3))) void*)(lds_raw + _sl + 32768 +              \
                                                    _st * 4096 + dT),                    \
          16, 0, 0);                                                                     \
    }                                                                                    \
  }

template <typename CT, bool FUSE>
__global__ __launch_bounds__(256, 1) void gemm256(
    const __hip_bfloat16* __restrict__ A, const __hip_bfloat16* __restrict__ Bw,
    CT* __restrict__ Cp, int N, int K, int kLen,
    __hip_bfloat16* __restrict__ A3out) {
  __shared__ __align__(16) char lds_raw[2 * SLOT];  // 128 KB

  const int tid = threadIdx.x;
  const int wid = tid >> 6, lane = tid & 63;
  const int wr = wid >> 1, wc = wid & 1;  // 2M x 2N waves, 128x128 tiles

  // bijective XCD swizzle (T1); all grids have nwg % 8 == 0
  const int nwg = gridDim.x * gridDim.y;
  const int orig = blockIdx.y * gridDim.x + blockIdx.x;
  const int q = nwg >> 3, r = nwg & 7;
  const int xcd = orig & 7, lid = orig >> 3;
  const int wg = (xcd < r ? xcd * (q + 1) : r * (q + 1) + (xcd - r) * q) + lid;
  const int bx = wg % gridDim.x, by = wg / gridDim.x;

  const size_t brow = (size_t)by * 256;
  const size_t bcol = (size_t)bx * 256;
  const int kStart = (int)blockIdx.z * kLen;
  const int NT = kLen / 64;

  // staging addressing (256 threads; site = 32 rows)
  const int kbx = (tid & 7) ^ ((tid >> 3) & 7);  // source 16B-group in 128B row
  const int rsit = tid >> 3;                     // row within 32-row site
  const size_t strideS = (size_t)K * 64;         // 32 rows * K * 2B
  const char* gA0 = (const char*)A +
      ((brow + (size_t)rsit) * (size_t)K + kStart + kbx * 8) * 2;
  const char* gB0 = (const char*)Bw +
      ((bcol + (size_t)rsit) * (size_t)K + kStart + kbx * 8) * 2;
  const int dT = tid * 16;

  // frag read offsets: row*128 + ((s*4 + (lane>>4)) ^ (lane&7)) * 16
  const int gx0 = (((lane >> 4) ^ (lane & 7))) * 16;
  const int gx1 = ((((lane >> 4) + 4) ^ (lane & 7))) * 16;
  const int arow = (wr * 128 + (lane & 15)) * 128;
  const int brw = 32768 + (wc * 128 + (lane & 15)) * 128;

  f32x4 acc[8][8] = {};

  // prologue: stage tile 0, drain, barrier
  STAGE(0);
  asm volatile("s_waitcnt vmcnt(0)" ::: "memory");
  __builtin_amdgcn_s_barrier();

  for (int T = 0; T < NT; ++T) {
    if (T + 1 < NT) STAGE(T + 1);

    const int sl = (T & 1) * SLOT;
    bf16x8 af[8], bfr[8];
    // ---- K-half 0
#pragma unroll
    for (int mf = 0; mf < 8; ++mf)
      af[mf] = *(const bf16x8*)(lds_raw + sl + arow + mf * 2048 + gx0);
#pragma unroll
    for (int nf = 0; nf < 8; ++nf)
      bfr[nf] = *(const bf16x8*)(lds_raw + sl + brw + nf * 2048 + gx0);
    __builtin_amdgcn_s_setprio(1);
#pragma unroll
    for (int mf = 0; mf < 8; ++mf)
#pragma unroll
      for (int nf = 0; nf < 8; ++nf)
        acc[mf][nf] =
            __builtin_amdgcn_mfma_f32_16x16x32_bf16(af[mf], bfr[nf], acc[mf][nf], 0, 0, 0);
    __builtin_amdgcn_s_setprio(0);
    // ---- K-half 1
#pragma unroll
    for (int mf = 0; mf < 8; ++mf)
      af[mf] = *(const bf16x8*)(lds_raw + sl + arow + mf * 2048 + gx1);
#pragma unroll
    for (int nf = 0; nf < 8; ++nf)
      bfr[nf] = *(const bf16x8*)(lds_raw + sl + brw + nf * 2048 + gx1);
    __builtin_amdgcn_s_setprio(1);
#pragma unroll
    for (int mf = 0; mf < 8; ++mf)
#pragma unroll
      for (int nf = 0; nf < 8; ++nf)
        acc[mf][nf] =
            __builtin_amdgcn_mfma_f32_16x16x32_bf16(af[mf], bfr[nf], acc[mf][nf], 0, 0, 0);
    __builtin_amdgcn_s_setprio(0);

    // one drain + barrier per K-64 tile (stage was issued a full tile ago)
    asm volatile("s_waitcnt vmcnt(0)" ::: "memory");
    asm volatile("s_waitcnt lgkmcnt(0)" ::: "memory");
    __builtin_amdgcn_s_barrier();
  }

  if constexpr (FUSE) {
    // ---- GLU + KAN-feature epilogue -> A3 (interleaved cols: 2p=w1, 2p+1=w2)
    float* gbuf = (float*)lds_raw;  // 16 slices x 16 rows x 128 pairs f32 = 128KB
#pragma unroll
    for (int mf = 0; mf < 8; ++mf) {
      const int s = wr * 8 + mf;
#pragma unroll
      for (int nf = 0; nf < 8; ++nf) {
#pragma unroll
        for (int rr = 0; rr < 4; ++rr) {
          float v = acc[mf][nf][rr];
          float w = __shfl_xor(v, 1, 64);
          if (!(lane & 1)) {
            const int r4 = (lane >> 4) * 4 + rr;
            const int ploc = wc * 64 + nf * 8 + ((lane & 14) >> 1);
            gbuf[s * 2048 + r4 * 128 + ploc] = v * w;
          }
        }
      }
    }
    __builtin_amdgcn_s_barrier();
    const int p2 = tid & 63;   // pair-pair index (handles pairs 2p2, 2p2+1)
    const int rb = tid >> 6;   // base row 0..3
    for (int k = 0; k < 64; ++k) {
      const int rr_ = rb + 4 * k;  // 0..255
      const int s = rr_ >> 4, rl = rr_ & 15;
      float g0 = gbuf[s * 2048 + rl * 128 + 2 * p2];
      float g1 = gbuf[s * 2048 + rl * 128 + 2 * p2 + 1];
      unsigned short h[18];
      kan_feat_u(g0, h);
      kan_feat_u(g1, h + 9);
      const size_t n = brow + rr_;
      const size_t pg = (bcol >> 1) + 2 * p2;
      uint32_t* dst = (uint32_t*)(A3out + n * (size_t)K3 + pg * NC);
#pragma unroll
      for (int qq = 0; qq < 9; ++qq)
        dst[qq] = (uint32_t)h[2 * qq] | ((uint32_t)h[2 * qq + 1] << 16);
    }
  } else {
    // plain epilogue: C/D layout col=lane&15, row=(lane>>4)*4+r
#pragma unroll
    for (int mf = 0; mf < 8; ++mf)
#pragma unroll
      for (int nf = 0; nf < 8; ++nf) {
        const size_t r0 = brow + wr * 128 + mf * 16 + (lane >> 4) * 4;
        const size_t c0 = bcol + wc * 128 + nf * 16 + (lane & 15);
        const size_t M = (size_t)gridDim.y * 256;
        CT* C = Cp + (size_t)blockIdx.z * M * (size_t)N;
#pragma unroll
        for (int rr = 0; rr < 4; ++rr) {
          float v = acc[mf][nf][rr];
          if constexpr (std::is_same<CT, float>::value)
            C[(r0 + rr) * (size_t)N + c0] = v;
          else
            C[(r0 + rr) * (size_t)N + c0] = __float2bfloat16(v);
        }
      }
  }
}

// sum nslice split-K partials (float4-vectorized)
__global__ void reduceK(const float* __restrict__ P, float* __restrict__ out,
                        size_t quarter, int nslice) {
  size_t t = (size_t)blockIdx.x * blockDim.x + threadIdx.x;
  if (t >= quarter) return;
  const float4* p = (const float4*)P;
  float4 a = p[t];
  for (int s = 1; s < nslice; ++s) {
    float4 b = p[(size_t)s * quarter + t];
    a.x += b.x; a.y += b.y; a.z += b.z; a.w += b.w;
  }
  ((float4*)out)[t] = a;
}

// ---------------------------------------------------------------------------
extern "C" void kernel_launch(void* const* d_in, const int* in_sizes, int n_in,
                              void* d_out, int out_size, void* d_ws, size_t ws_size,
                              hipStream_t stream) {
  const float* x   = (const float*)d_in[0];
  const float* bw1 = (const float*)d_in[1];
  const float* sw1 = (const float*)d_in[2];
  const float* bw2 = (const float*)d_in[3];
  const float* sw2 = (const float*)d_in[4];
  const float* bw3 = (const float*)d_in[5];
  const float* sw3 = (const float*)d_in[6];
  float* out = (float*)d_out;
  char* ws = (char*)d_ws;

  const size_t W12_B  = (size_t)8192 * K1 * 2;   // 150,994,944
  const size_t A1_B   = (size_t)NTOK * K1 * 2;   //  75,497,472
  const size_t A3F_B  = (size_t)NTOK * K3 * 2;   // 301,989,888
  const size_t A3C_B  = (size_t)CHUNK * K3 * 2;  //  75,497,472
  const size_t HF32_B = (size_t)NTOK * 8192 * 4; // 134,217,728

  const bool fused = ws_size >= W12_B + A1_B + A3F_B;  // 528,482,304
  const bool hF32  = ws_size >= W12_B + A1_B + HF32_B; // 360,710,144 (fallback)

  __hip_bfloat16* W12 = (__hip_bfloat16*)(ws);
  __hip_bfloat16* A1  = (__hip_bfloat16*)(ws + W12_B);
  __hip_bfloat16* W3  = A1;  // A1 dead after GEMM1

  size_t pairs12 = (size_t)D_FF * D_MODEL / 2;
  int blocks12 = (int)((pairs12 + 255) / 256);
  size_t pairs3 = (size_t)D_MODEL * D_FF / 2;
  int blocks3 = (int)((pairs3 + 255) / 256);
  size_t pairsA1 = (size_t)NTOK * D_MODEL / 2;

  if (fused) {
    __hip_bfloat16* A3f = (__hip_bfloat16*)(ws + W12_B + A1_B);
    float*          Par = (float*)(ws);  // reuses W12 region after GEMM1

    pack_kan_w<<<blocks12, 256, 0, stream>>>(bw1, sw1, W12, K1, 10, 2, 0, pairs12);
    pack_kan_w<<<blocks12, 256, 0, stream>>>(bw2, sw2, W12, K1, 10, 2, 1, pairs12);
    build_a1<<<(int)((pairsA1 + 255) / 256), 256, 0, stream>>>(x, A1);
    gemm256<float, true><<<dim3(8192 / 256, NTOK / 256, 1), 256, 0, stream>>>(
        A1, W12, nullptr, 8192, K1, K1, A3f);
    pack_kan_w<<<blocks3, 256, 0, stream>>>(bw3, sw3, W3, K3, 12, 1, 0, pairs3);
    gemm256<float, false><<<dim3(D_MODEL / 256, NTOK / 256, SPLITKF), 256, 0, stream>>>(
        A3f, W3, Par, D_MODEL, K3, K3 / SPLITKF, nullptr);
    size_t quarter = (size_t)NTOK * D_MODEL / 4;
    reduceK<<<(int)((quarter + 255) / 256), 256, 0, stream>>>(Par, out, quarter, SPLITKF);
  } else {
    void*           Hv  = (void*)(ws + W12_B + A1_B);
    __hip_bfloat16* A3c = (__hip_bfloat16*)(ws);        // W12 dead after GEMM1
    float*          Par = (float*)(ws + A3C_B);

    pack_kan_w<<<blocks12, 256, 0, stream>>>(bw1, sw1, W12, K1, 10, 1, 0, pairs12);
    pack_kan_w<<<blocks12, 256, 0, stream>>>(bw2, sw2, W12, K1, 10, 1, 4096, pairs12);
    build_a1<<<(int)((pairsA1 + 255) / 256), 256, 0, stream>>>(x, A1);
    if (hF32)
      gemm256<float, false><<<dim3(8192 / 256, NTOK / 256, 1), 256, 0, stream>>>(
          A1, W12, (float*)Hv, 8192, K1, K1, nullptr);
    else
      gemm256<__hip_bfloat16, false><<<dim3(8192 / 256, NTOK / 256, 1), 256, 0, stream>>>(
          A1, W12, (__hip_bfloat16*)Hv, 8192, K1, K1, nullptr);
    pack_kan_w<<<blocks3, 256, 0, stream>>>(bw3, sw3, W3, K3, 12, 1, 0, pairs3);
    for (int c = 0; c < NTOK / CHUNK; ++c) {
      size_t pairsG = (size_t)CHUNK * D_FF / 2;
      int blocksG = (int)((pairsG + 255) / 256);
      if (hF32)
        glu_a3<float><<<blocksG, 256, 0, stream>>>(
            (const float*)Hv + (size_t)c * CHUNK * 8192, A3c);
      else
        glu_a3<__hip_bfloat16><<<blocksG, 256, 0, stream>>>(
            (const __hip_bfloat16*)Hv + (size_t)c * CHUNK * 8192, A3c);
      gemm256<float, false><<<dim3(D_MODEL / 256, CHUNK / 256, SPLITK2), 256, 0, stream>>>(
          A3c, W3, Par, D_MODEL, K3, K3 / SPLITK2, nullptr);
      size_t quarter = (size_t)CHUNK * D_MODEL / 4;
      reduceK<<<(int)((quarter + 255) / 256), 256, 0, stream>>>(
          Par, out + (size_t)c * CHUNK * D_MODEL, quarter, SPLITK2);
    }
  }
}

// Round 16
// 1039.365 us; speedup vs baseline: 1.1102x; 1.1102x over previous
//
#include <hip/hip_runtime.h>
#include <hip/hip_bf16.h>
#include <cstdint>
#include <cstddef>
#include <type_traits>

// KAN GLU expert: h = kan(x;w1) * kan(x;w2); out = kan(h;w3)
// kan(x;W) == [silu(x_i), B0..B7(x_i)]_i @ [base_w | spline_w]^T
// -> bf16 MFMA GEMMs with K expanded 9x.
//
// FINAL (R16 = proven R12/R14): 256x256 block, 8 waves (2Mx4N), wave tile
// 128x64, BK=64, ring-2 LDS slots of 64KB (128KB total), 16x16x32 MFMA,
// ONE vmcnt(0)+barrier per K-64 tile (stage issued a full tile ahead).
// 128B LDS rows; swizzle: physical 16B-group gp = gl ^ (row&7), staged via
// pre-swizzled global source; read pattern measured conflict-free.
// Fused path: GEMM1 epilogue does GLU (interleaved W12 rows, shfl_xor)
// + KAN features -> A3 directly (no H). GEMM2 single dispatch split-K=4.

#define D_MODEL 1024
#define D_FF    4096
#define NTOK    4096
#define NC      9
#define K1      (D_MODEL * NC)  // 9216
#define K3      (D_FF * NC)     // 36864
#define SPLITK2 16              // fallback chunked GEMM2
#define SPLITKF 4               // fused full GEMM2
#define CHUNK   1024
#define SLOT    65536           // ring-2 slot: A 32KB + B 32KB

typedef __attribute__((ext_vector_type(8))) short bf16x8;
typedef __attribute__((ext_vector_type(4))) float f32x4;

__device__ __forceinline__ unsigned short bf16b(float f) {
  __hip_bfloat16 h = __float2bfloat16(f);
  return __builtin_bit_cast(unsigned short, h);
}

// ---------------------------------------------------------------------------
// silu + 8 cubic B-spline bases on uniform grid t_m = 0.4*m - 2.2
// ---------------------------------------------------------------------------
__device__ __forceinline__ void kan_feat_u(float x, unsigned short* dst) {
  float s = x / (1.0f + __expf(-x));
  float B[11];
#pragma unroll
  for (int j = 0; j < 11; ++j) {
    float gj = -2.2f + 0.4f * j;
    B[j] = (x >= gj && x < gj + 0.4f) ? 1.0f : 0.0f;
  }
#pragma unroll
  for (int p = 1; p <= 3; ++p) {
    float inv = 1.0f / (0.4f * p);
#pragma unroll
    for (int i = 0; i + p < 11; ++i) {
      float gi = -2.2f + 0.4f * i;
      B[i] = (x - gi) * inv * B[i] + ((gi + 0.4f + 0.4f * p) - x) * inv * B[i + 1];
    }
  }
  dst[0] = bf16b(s);
#pragma unroll
  for (int c = 0; c < 8; ++c) dst[1 + c] = bf16b(B[c]);
}

// ---------------------------------------------------------------------------
// Pack two adjacent input-features per thread -> 9 dword stores.
// dst row = o*rowMul + rowBase (rowMul=2 interleaves two layers).
// ---------------------------------------------------------------------------
__global__ void pack_kan_w(const float* __restrict__ bw, const float* __restrict__ sw,
                           __hip_bfloat16* __restrict__ W, int K, int inShift,
                           int rowMul, int rowBase, size_t totalPairs) {
  size_t t = (size_t)blockIdx.x * blockDim.x + threadIdx.x;
  if (t >= totalPairs) return;
  size_t o = t >> (inShift - 1);
  size_t ip = (t & (((size_t)1 << (inShift - 1)) - 1)) * 2;
  size_t e0 = (o << inShift) + ip;
  float2 b = *(const float2*)(bw + e0);
  const float4* sp = (const float4*)(sw + e0 * 8);
  float4 s0 = sp[0], s1 = sp[1], s2 = sp[2], s3 = sp[3];
  unsigned short h[18];
  h[0] = bf16b(b.x);
  h[1] = bf16b(s0.x); h[2] = bf16b(s0.y); h[3] = bf16b(s0.z); h[4] = bf16b(s0.w);
  h[5] = bf16b(s1.x); h[6] = bf16b(s1.y); h[7] = bf16b(s1.z); h[8] = bf16b(s1.w);
  h[9] = bf16b(b.y);
  h[10] = bf16b(s2.x); h[11] = bf16b(s2.y); h[12] = bf16b(s2.z); h[13] = bf16b(s2.w);
  h[14] = bf16b(s3.x); h[15] = bf16b(s3.y); h[16] = bf16b(s3.z); h[17] = bf16b(s3.w);
  uint32_t* dst = (uint32_t*)(W + (o * rowMul + rowBase) * (size_t)K + ip * NC);
#pragma unroll
  for (int k = 0; k < 9; ++k) dst[k] = (uint32_t)h[2 * k] | ((uint32_t)h[2 * k + 1] << 16);
}

// A1 from x; two elements per thread
__global__ void build_a1(const float* __restrict__ x, __hip_bfloat16* __restrict__ A1) {
  size_t t = (size_t)blockIdx.x * blockDim.x + threadIdx.x;
  if (t >= (size_t)NTOK * D_MODEL / 2) return;
  size_t n = t >> 9;
  size_t ip = (t & 511) * 2;
  float2 xv = *(const float2*)(x + n * D_MODEL + ip);
  unsigned short h[18];
  kan_feat_u(xv.x, h);
  kan_feat_u(xv.y, h + 9);
  uint32_t* dst = (uint32_t*)(A1 + n * (size_t)K1 + ip * NC);
#pragma unroll
  for (int k = 0; k < 9; ++k) dst[k] = (uint32_t)h[2 * k] | ((uint32_t)h[2 * k + 1] << 16);
}

// fallback only: h = Hc[:, :4096] * Hc[:, 4096:]; two j per thread
template <typename HT>
__global__ void glu_a3(const HT* __restrict__ Hc, __hip_bfloat16* __restrict__ A3c) {
  size_t t = (size_t)blockIdx.x * blockDim.x + threadIdx.x;
  if (t >= (size_t)CHUNK * D_FF / 2) return;
  size_t n = t >> 11;
  size_t jp = (t & 2047) * 2;
  float a0, a1, c0, c1;
  if constexpr (std::is_same<HT, float>::value) {
    float2 u = *(const float2*)(Hc + n * 8192 + jp);
    float2 v = *(const float2*)(Hc + n * 8192 + 4096 + jp);
    a0 = u.x; a1 = u.y; c0 = v.x; c1 = v.y;
  } else {
    a0 = __bfloat162float(Hc[n * 8192 + jp]);
    a1 = __bfloat162float(Hc[n * 8192 + jp + 1]);
    c0 = __bfloat162float(Hc[n * 8192 + 4096 + jp]);
    c1 = __bfloat162float(Hc[n * 8192 + 4096 + jp + 1]);
  }
  unsigned short h[18];
  kan_feat_u(a0 * c0, h);
  kan_feat_u(a1 * c1, h + 9);
  uint32_t* dst = (uint32_t*)(A3c + n * (size_t)K3 + jp * NC);
#pragma unroll
  for (int k = 0; k < 9; ++k) dst[k] = (uint32_t)h[2 * k] | ((uint32_t)h[2 * k + 1] << 16);
}

// ---------------------------------------------------------------------------
// 256x256 bf16 GEMM, BK=64, ring-2. C = A (M x K, rm) * Bw^T (Bw: N x K, rm).
// Staging per tile: 8 sites x (512thr x 16B) = 64KB. Site s covers 64 rows.
// Per-lane: row = wid*8 + (lane>>3), source k-group (lane&7)^(lane>>3);
// LDS dest linear (wave base + lane*16) => physical gp = gl ^ (row&7).
// ---------------------------------------------------------------------------
#define STAGE(Ts)                                                                        \
  {                                                                                      \
    const int _sl = ((Ts) & 1) * SLOT;                                                   \
    const size_t _ko = (size_t)(Ts) * 128;                                               \
    _Pragma("unroll") for (int _st = 0; _st < 4; ++_st) {                                \
      __builtin_amdgcn_global_load_lds(                                                  \
          (const __attribute__((address_space(1))) void*)(gA0 + _st * strideK + _ko),    \
          (__attribute__((address_space(3))) void*)(lds_raw + _sl + _st * 8192 + dW),    \
          16, 0, 0);                                                                     \
      __builtin_amdgcn_global_load_lds(                                                  \
          (const __attribute__((address_space(1))) void*)(gB0 + _st * strideK + _ko),    \
          (__attribute__((address_space(3))) void*)(lds_raw + _sl + 32768 +              \
                                                    _st * 8192 + dW),                    \
          16, 0, 0);                                                                     \
    }                                                                                    \
  }

template <typename CT, bool FUSE>
__global__ __launch_bounds__(512, 2) void gemm256(
    const __hip_bfloat16* __restrict__ A, const __hip_bfloat16* __restrict__ Bw,
    CT* __restrict__ Cp, int N, int K, int kLen,
    __hip_bfloat16* __restrict__ A3out) {
  __shared__ __align__(16) char lds_raw[2 * SLOT];  // 128 KB

  const int tid = threadIdx.x;
  const int wid = tid >> 6, lane = tid & 63;
  const int wr = wid >> 2, wc = wid & 3;  // 2M x 4N waves, 128x64 tiles

  // bijective XCD swizzle (T1); all grids have nwg % 8 == 0
  const int nwg = gridDim.x * gridDim.y;
  const int orig = blockIdx.y * gridDim.x + blockIdx.x;
  const int q = nwg >> 3, r = nwg & 7;
  const int xcd = orig & 7, lid = orig >> 3;
  const int wg = (xcd < r ? xcd * (q + 1) : r * (q + 1) + (xcd - r) * q) + lid;
  const int bx = wg % gridDim.x, by = wg / gridDim.x;

  const size_t brow = (size_t)by * 256;
  const size_t bcol = (size_t)bx * 256;
  const int kStart = (int)blockIdx.z * kLen;
  const int NT = kLen / 64;

  // staging addressing
  const int kbx = (lane & 7) ^ (lane >> 3);  // source 16B-group within 128B row
  const int rsub = lane >> 3;                // row within 8-row wave stripe
  const size_t strideK = (size_t)K * 128;    // 64 rows * K * 2B
  const char* gA0 = (const char*)A +
      ((brow + (size_t)(wid * 8 + rsub)) * (size_t)K + kStart + kbx * 8) * 2;
  const char* gB0 = (const char*)Bw +
      ((bcol + (size_t)(wid * 8 + rsub)) * (size_t)K + kStart + kbx * 8) * 2;
  const int dW = wid * 1024;

  // frag read offsets: row*128 + ((s*4 + (lane>>4)) ^ (lane&7)) * 16
  const int gx0 = (((lane >> 4) ^ (lane & 7))) * 16;
  const int gx1 = ((((lane >> 4) + 4) ^ (lane & 7))) * 16;
  const int arow = (wr * 128 + (lane & 15)) * 128;
  const int brw = 32768 + (wc * 64 + (lane & 15)) * 128;

  f32x4 acc[8][4] = {};

  // prologue: stage tile 0, drain, barrier
  STAGE(0);
  asm volatile("s_waitcnt vmcnt(0)" ::: "memory");
  __builtin_amdgcn_s_barrier();

  for (int T = 0; T < NT; ++T) {
    if (T + 1 < NT) STAGE(T + 1);

    const int sl = (T & 1) * SLOT;
    bf16x8 af[8], bfr[4];
    // ---- K-half 0
#pragma unroll
    for (int mf = 0; mf < 8; ++mf)
      af[mf] = *(const bf16x8*)(lds_raw + sl + arow + mf * 2048 + gx0);
#pragma unroll
    for (int nf = 0; nf < 4; ++nf)
      bfr[nf] = *(const bf16x8*)(lds_raw + sl + brw + nf * 2048 + gx0);
    __builtin_amdgcn_s_setprio(1);
#pragma unroll
    for (int mf = 0; mf < 8; ++mf)
#pragma unroll
      for (int nf = 0; nf < 4; ++nf)
        acc[mf][nf] =
            __builtin_amdgcn_mfma_f32_16x16x32_bf16(af[mf], bfr[nf], acc[mf][nf], 0, 0, 0);
    __builtin_amdgcn_s_setprio(0);
    // ---- K-half 1
#pragma unroll
    for (int mf = 0; mf < 8; ++mf)
      af[mf] = *(const bf16x8*)(lds_raw + sl + arow + mf * 2048 + gx1);
#pragma unroll
    for (int nf = 0; nf < 4; ++nf)
      bfr[nf] = *(const bf16x8*)(lds_raw + sl + brw + nf * 2048 + gx1);
    __builtin_amdgcn_s_setprio(1);
#pragma unroll
    for (int mf = 0; mf < 8; ++mf)
#pragma unroll
      for (int nf = 0; nf < 4; ++nf)
        acc[mf][nf] =
            __builtin_amdgcn_mfma_f32_16x16x32_bf16(af[mf], bfr[nf], acc[mf][nf], 0, 0, 0);
    __builtin_amdgcn_s_setprio(0);

    // one drain + barrier per K-64 tile (stage was issued a full tile ago)
    asm volatile("s_waitcnt vmcnt(0)" ::: "memory");
    asm volatile("s_waitcnt lgkmcnt(0)" ::: "memory");
    __builtin_amdgcn_s_barrier();
  }

  if constexpr (FUSE) {
    // ---- GLU + KAN-feature epilogue -> A3 (interleaved cols: 2p=w1, 2p+1=w2)
    float* gbuf = (float*)lds_raw;  // 16 slices x 16 rows x 128 pairs f32 = 128KB
#pragma unroll
    for (int mf = 0; mf < 8; ++mf) {
      const int s = wr * 8 + mf;
#pragma unroll
      for (int nf = 0; nf < 4; ++nf) {
#pragma unroll
        for (int rr = 0; rr < 4; ++rr) {
          float v = acc[mf][nf][rr];
          float w = __shfl_xor(v, 1, 64);
          if (!(lane & 1)) {
            const int r4 = (lane >> 4) * 4 + rr;
            const int ploc = wc * 32 + nf * 8 + ((lane & 14) >> 1);
            gbuf[s * 2048 + r4 * 128 + ploc] = v * w;
          }
        }
      }
    }
    __builtin_amdgcn_s_barrier();
    const int p2 = tid & 63;   // pair-pair index (handles pairs 2p2, 2p2+1)
    const int rb = tid >> 6;   // base row
    for (int k = 0; k < 32; ++k) {
      const int rr_ = rb + 8 * k;  // 0..255
      const int s = rr_ >> 4, rl = rr_ & 15;
      float g0 = gbuf[s * 2048 + rl * 128 + 2 * p2];
      float g1 = gbuf[s * 2048 + rl * 128 + 2 * p2 + 1];
      unsigned short h[18];
      kan_feat_u(g0, h);
      kan_feat_u(g1, h + 9);
      const size_t n = brow + rr_;
      const size_t pg = (bcol >> 1) + 2 * p2;
      uint32_t* dst = (uint32_t*)(A3out + n * (size_t)K3 + pg * NC);
#pragma unroll
      for (int qq = 0; qq < 9; ++qq)
        dst[qq] = (uint32_t)h[2 * qq] | ((uint32_t)h[2 * qq + 1] << 16);
    }
  } else {
    // plain epilogue: C/D layout col=lane&15, row=(lane>>4)*4+r
#pragma unroll
    for (int mf = 0; mf < 8; ++mf)
#pragma unroll
      for (int nf = 0; nf < 4; ++nf) {
        const size_t r0 = brow + wr * 128 + mf * 16 + (lane >> 4) * 4;
        const size_t c0 = bcol + wc * 64 + nf * 16 + (lane & 15);
        const size_t M = (size_t)gridDim.y * 256;
        CT* C = Cp + (size_t)blockIdx.z * M * (size_t)N;
#pragma unroll
        for (int rr = 0; rr < 4; ++rr) {
          float v = acc[mf][nf][rr];
          if constexpr (std::is_same<CT, float>::value)
            C[(r0 + rr) * (size_t)N + c0] = v;
          else
            C[(r0 + rr) * (size_t)N + c0] = __float2bfloat16(v);
        }
      }
  }
}

// sum nslice split-K partials (float4-vectorized)
__global__ void reduceK(const float* __restrict__ P, float* __restrict__ out,
                        size_t quarter, int nslice) {
  size_t t = (size_t)blockIdx.x * blockDim.x + threadIdx.x;
  if (t >= quarter) return;
  const float4* p = (const float4*)P;
  float4 a = p[t];
  for (int s = 1; s < nslice; ++s) {
    float4 b = p[(size_t)s * quarter + t];
    a.x += b.x; a.y += b.y; a.z += b.z; a.w += b.w;
  }
  ((float4*)out)[t] = a;
}

// ---------------------------------------------------------------------------
extern "C" void kernel_launch(void* const* d_in, const int* in_sizes, int n_in,
                              void* d_out, int out_size, void* d_ws, size_t ws_size,
                              hipStream_t stream) {
  const float* x   = (const float*)d_in[0];
  const float* bw1 = (const float*)d_in[1];
  const float* sw1 = (const float*)d_in[2];
  const float* bw2 = (const float*)d_in[3];
  const float* sw2 = (const float*)d_in[4];
  const float* bw3 = (const float*)d_in[5];
  const float* sw3 = (const float*)d_in[6];
  float* out = (float*)d_out;
  char* ws = (char*)d_ws;

  const size_t W12_B  = (size_t)8192 * K1 * 2;   // 150,994,944
  const size_t A1_B   = (size_t)NTOK * K1 * 2;   //  75,497,472
  const size_t A3F_B  = (size_t)NTOK * K3 * 2;   // 301,989,888
  const size_t A3C_B  = (size_t)CHUNK * K3 * 2;  //  75,497,472
  const size_t HF32_B = (size_t)NTOK * 8192 * 4; // 134,217,728

  const bool fused = ws_size >= W12_B + A1_B + A3F_B;  // 528,482,304
  const bool hF32  = ws_size >= W12_B + A1_B + HF32_B; // 360,710,144 (fallback)

  __hip_bfloat16* W12 = (__hip_bfloat16*)(ws);
  __hip_bfloat16* A1  = (__hip_bfloat16*)(ws + W12_B);
  __hip_bfloat16* W3  = A1;  // A1 dead after GEMM1

  size_t pairs12 = (size_t)D_FF * D_MODEL / 2;
  int blocks12 = (int)((pairs12 + 255) / 256);
  size_t pairs3 = (size_t)D_MODEL * D_FF / 2;
  int blocks3 = (int)((pairs3 + 255) / 256);
  size_t pairsA1 = (size_t)NTOK * D_MODEL / 2;

  if (fused) {
    __hip_bfloat16* A3f = (__hip_bfloat16*)(ws + W12_B + A1_B);
    float*          Par = (float*)(ws);  // reuses W12 region after GEMM1

    pack_kan_w<<<blocks12, 256, 0, stream>>>(bw1, sw1, W12, K1, 10, 2, 0, pairs12);
    pack_kan_w<<<blocks12, 256, 0, stream>>>(bw2, sw2, W12, K1, 10, 2, 1, pairs12);
    build_a1<<<(int)((pairsA1 + 255) / 256), 256, 0, stream>>>(x, A1);
    gemm256<float, true><<<dim3(8192 / 256, NTOK / 256, 1), 512, 0, stream>>>(
        A1, W12, nullptr, 8192, K1, K1, A3f);
    pack_kan_w<<<blocks3, 256, 0, stream>>>(bw3, sw3, W3, K3, 12, 1, 0, pairs3);
    gemm256<float, false><<<dim3(D_MODEL / 256, NTOK / 256, SPLITKF), 512, 0, stream>>>(
        A3f, W3, Par, D_MODEL, K3, K3 / SPLITKF, nullptr);
    size_t quarter = (size_t)NTOK * D_MODEL / 4;
    reduceK<<<(int)((quarter + 255) / 256), 256, 0, stream>>>(Par, out, quarter, SPLITKF);
  } else {
    void*           Hv  = (void*)(ws + W12_B + A1_B);
    __hip_bfloat16* A3c = (__hip_bfloat16*)(ws);        // W12 dead after GEMM1
    float*          Par = (float*)(ws + A3C_B);

    pack_kan_w<<<blocks12, 256, 0, stream>>>(bw1, sw1, W12, K1, 10, 1, 0, pairs12);
    pack_kan_w<<<blocks12, 256, 0, stream>>>(bw2, sw2, W12, K1, 10, 1, 4096, pairs12);
    build_a1<<<(int)((pairsA1 + 255) / 256), 256, 0, stream>>>(x, A1);
    if (hF32)
      gemm256<float, false><<<dim3(8192 / 256, NTOK / 256, 1), 512, 0, stream>>>(
          A1, W12, (float*)Hv, 8192, K1, K1, nullptr);
    else
      gemm256<__hip_bfloat16, false><<<dim3(8192 / 256, NTOK / 256, 1), 512, 0, stream>>>(
          A1, W12, (__hip_bfloat16*)Hv, 8192, K1, K1, nullptr);
    pack_kan_w<<<blocks3, 256, 0, stream>>>(bw3, sw3, W3, K3, 12, 1, 0, pairs3);
    for (int c = 0; c < NTOK / CHUNK; ++c) {
      size_t pairsG = (size_t)CHUNK * D_FF / 2;
      int blocksG = (int)((pairsG + 255) / 256);
      if (hF32)
        glu_a3<float><<<blocksG, 256, 0, stream>>>(
            (const float*)Hv + (size_t)c * CHUNK * 8192, A3c);
      else
        glu_a3<__hip_bfloat16><<<blocksG, 256, 0, stream>>>(
            (const __hip_bfloat16*)Hv + (size_t)c * CHUNK * 8192, A3c);
      gemm256<float, false><<<dim3(D_MODEL / 256, CHUNK / 256, SPLITK2), 512, 0, stream>>>(
          A3c, W3, Par, D_MODEL, K3, K3 / SPLITK2, nullptr);
      size_t quarter = (size_t)CHUNK * D_MODEL / 4;
      reduceK<<<(int)((quarter + 255) / 256), 256, 0, stream>>>(
          Par, out + (size_t)c * CHUNK * D_MODEL, quarter, SPLITK2);
    }
  }
}

// Round 17
// 1012.412 us; speedup vs baseline: 1.1398x; 1.0266x over previous
//
#include <hip/hip_runtime.h>
#include <hip/hip_bf16.h>
#include <cstdint>
#include <cstddef>
#include <type_traits>

// KAN GLU expert: h = kan(x;w1) * kan(x;w2); out = kan(h;w3)
// kan(x;W) == [silu(x_i), B0..B7(x_i)]_i @ [base_w | spline_w]^T
// -> bf16 MFMA GEMMs with K expanded 9x.
//
// R17 = R12 GEMM (proven: 256x256 block, 8 waves 2Mx4N, wave tile 128x64,
// BK=64, ring-2 64KB slots, 16x16x32 MFMA, one vmcnt(0)+barrier per K-step,
// swizzle gp = gl ^ (row&7), measured conflict-free) + PLANE-MAJOR K layout:
// k' = f*IN + j (feature plane f=0..8, column j). K is a reduction index so
// any permutation is valid when A and W share it. All feature producers
// (pack_kan_w, build_a1, glu_a3, fused epilogue) now write one dword per
// plane with lanes at adjacent j -> fully coalesced stores (was 36B-stride
// scatter = ~9x L2 write transactions + partial-line RMW).
// Fused path: GEMM1 epilogue does GLU (interleaved W12 rows, shfl_xor)
// + KAN features -> A3 directly (no H). GEMM2 single dispatch split-K=4.

#define D_MODEL 1024
#define D_FF    4096
#define NTOK    4096
#define NC      9
#define K1      (D_MODEL * NC)  // 9216
#define K3      (D_FF * NC)     // 36864
#define SPLITK2 16              // fallback chunked GEMM2
#define SPLITKF 4               // fused full GEMM2
#define CHUNK   1024
#define SLOT    65536           // ring-2 slot: A 32KB + B 32KB

typedef __attribute__((ext_vector_type(8))) short bf16x8;
typedef __attribute__((ext_vector_type(4))) float f32x4;

__device__ __forceinline__ unsigned short bf16b(float f) {
  __hip_bfloat16 h = __float2bfloat16(f);
  return __builtin_bit_cast(unsigned short, h);
}
__device__ __forceinline__ uint32_t pk2(float a, float b) {
  return (uint32_t)bf16b(a) | ((uint32_t)bf16b(b) << 16);
}

// ---------------------------------------------------------------------------
// silu + 8 cubic B-spline bases on uniform grid t_m = 0.4*m - 2.2
// ---------------------------------------------------------------------------
__device__ __forceinline__ void kan_feat_u(float x, unsigned short* dst) {
  float s = x / (1.0f + __expf(-x));
  float B[11];
#pragma unroll
  for (int j = 0; j < 11; ++j) {
    float gj = -2.2f + 0.4f * j;
    B[j] = (x >= gj && x < gj + 0.4f) ? 1.0f : 0.0f;
  }
#pragma unroll
  for (int p = 1; p <= 3; ++p) {
    float inv = 1.0f / (0.4f * p);
#pragma unroll
    for (int i = 0; i + p < 11; ++i) {
      float gi = -2.2f + 0.4f * i;
      B[i] = (x - gi) * inv * B[i] + ((gi + 0.4f + 0.4f * p) - x) * inv * B[i + 1];
    }
  }
  dst[0] = bf16b(s);
#pragma unroll
  for (int c = 0; c < 8; ++c) dst[1 + c] = bf16b(B[c]);
}

// ---------------------------------------------------------------------------
// Pack weights, PLANE-MAJOR: W[row][f*IN + j]. One thread = one (o, j-pair),
// 9 coalesced dword stores (plane stride IN/2 dwords).
// dst row = o*rowMul + rowBase (rowMul=2 interleaves two layers).
// ---------------------------------------------------------------------------
__global__ void pack_kan_w(const float* __restrict__ bw, const float* __restrict__ sw,
                           __hip_bfloat16* __restrict__ W, int K, int inShift,
                           int rowMul, int rowBase, size_t totalPairs) {
  size_t t = (size_t)blockIdx.x * blockDim.x + threadIdx.x;
  if (t >= totalPairs) return;
  const int halfShift = inShift - 1;
  size_t o = t >> halfShift;
  size_t p = t & (((size_t)1 << halfShift) - 1);
  size_t e0 = (o << inShift) + 2 * p;
  float2 b = *(const float2*)(bw + e0);
  const float4* sp = (const float4*)(sw + e0 * 8);
  float4 s0 = sp[0], s1 = sp[1], s2 = sp[2], s3 = sp[3];  // s0,s1: elem e0; s2,s3: e0+1
  const size_t HP = (size_t)1 << halfShift;  // pairs per plane
  uint32_t* dst = (uint32_t*)(W + (o * rowMul + rowBase) * (size_t)K);
  dst[p]          = pk2(b.x, b.y);
  dst[1 * HP + p] = pk2(s0.x, s2.x);
  dst[2 * HP + p] = pk2(s0.y, s2.y);
  dst[3 * HP + p] = pk2(s0.z, s2.z);
  dst[4 * HP + p] = pk2(s0.w, s2.w);
  dst[5 * HP + p] = pk2(s1.x, s3.x);
  dst[6 * HP + p] = pk2(s1.y, s3.y);
  dst[7 * HP + p] = pk2(s1.z, s3.z);
  dst[8 * HP + p] = pk2(s1.w, s3.w);
}

// A1 plane-major: A1[n][f*1024 + i]; thread = (n, i-pair), 9 coalesced stores
__global__ void build_a1(const float* __restrict__ x, __hip_bfloat16* __restrict__ A1) {
  size_t t = (size_t)blockIdx.x * blockDim.x + threadIdx.x;
  if (t >= (size_t)NTOK * D_MODEL / 2) return;
  size_t n = t >> 9;
  size_t p = t & 511;
  float2 xv = *(const float2*)(x + n * D_MODEL + 2 * p);
  unsigned short h0[9], h1[9];
  kan_feat_u(xv.x, h0);
  kan_feat_u(xv.y, h1);
  uint32_t* dst = (uint32_t*)(A1 + n * (size_t)K1);
#pragma unroll
  for (int f = 0; f < 9; ++f)
    dst[(size_t)f * 512 + p] = (uint32_t)h0[f] | ((uint32_t)h1[f] << 16);
}

// fallback only: h = Hc[:, :4096] * Hc[:, 4096:]; A3 plane-major
template <typename HT>
__global__ void glu_a3(const HT* __restrict__ Hc, __hip_bfloat16* __restrict__ A3c) {
  size_t t = (size_t)blockIdx.x * blockDim.x + threadIdx.x;
  if (t >= (size_t)CHUNK * D_FF / 2) return;
  size_t n = t >> 11;
  size_t p = t & 2047;
  float a0, a1, c0, c1;
  if constexpr (std::is_same<HT, float>::value) {
    float2 u = *(const float2*)(Hc + n * 8192 + 2 * p);
    float2 v = *(const float2*)(Hc + n * 8192 + 4096 + 2 * p);
    a0 = u.x; a1 = u.y; c0 = v.x; c1 = v.y;
  } else {
    a0 = __bfloat162float(Hc[n * 8192 + 2 * p]);
    a1 = __bfloat162float(Hc[n * 8192 + 2 * p + 1]);
    c0 = __bfloat162float(Hc[n * 8192 + 4096 + 2 * p]);
    c1 = __bfloat162float(Hc[n * 8192 + 4096 + 2 * p + 1]);
  }
  unsigned short h0[9], h1[9];
  kan_feat_u(a0 * c0, h0);
  kan_feat_u(a1 * c1, h1);
  uint32_t* dst = (uint32_t*)(A3c + n * (size_t)K3);
#pragma unroll
  for (int f = 0; f < 9; ++f)
    dst[(size_t)f * 2048 + p] = (uint32_t)h0[f] | ((uint32_t)h1[f] << 16);
}

// ---------------------------------------------------------------------------
// 256x256 bf16 GEMM, BK=64, ring-2. C = A (M x K, rm) * Bw^T (Bw: N x K, rm).
// Staging per tile: 8 sites x (512thr x 16B) = 64KB. Site s covers 64 rows.
// Per-lane: row = wid*8 + (lane>>3), source k-group (lane&7)^(lane>>3);
// LDS dest linear (wave base + lane*16) => physical gp = gl ^ (row&7).
// ---------------------------------------------------------------------------
#define STAGE(Ts)                                                                        \
  {                                                                                      \
    const int _sl = ((Ts) & 1) * SLOT;                                                   \
    const size_t _ko = (size_t)(Ts) * 128;                                               \
    _Pragma("unroll") for (int _st = 0; _st < 4; ++_st) {                                \
      __builtin_amdgcn_global_load_lds(                                                  \
          (const __attribute__((address_space(1))) void*)(gA0 + _st * strideK + _ko),    \
          (__attribute__((address_space(3))) void*)(lds_raw + _sl + _st * 8192 + dW),    \
          16, 0, 0);                                                                     \
      __builtin_amdgcn_global_load_lds(                                                  \
          (const __attribute__((address_space(1))) void*)(gB0 + _st * strideK + _ko),    \
          (__attribute__((address_space(3))) void*)(lds_raw + _sl + 32768 +              \
                                                    _st * 8192 + dW),                    \
          16, 0, 0);                                                                     \
    }                                                                                    \
  }

template <typename CT, bool FUSE>
__global__ __launch_bounds__(512, 2) void gemm256(
    const __hip_bfloat16* __restrict__ A, const __hip_bfloat16* __restrict__ Bw,
    CT* __restrict__ Cp, int N, int K, int kLen,
    __hip_bfloat16* __restrict__ A3out) {
  __shared__ __align__(16) char lds_raw[2 * SLOT];  // 128 KB

  const int tid = threadIdx.x;
  const int wid = tid >> 6, lane = tid & 63;
  const int wr = wid >> 2, wc = wid & 3;  // 2M x 4N waves, 128x64 tiles

  // bijective XCD swizzle (T1); all grids have nwg % 8 == 0
  const int nwg = gridDim.x * gridDim.y;
  const int orig = blockIdx.y * gridDim.x + blockIdx.x;
  const int q = nwg >> 3, r = nwg & 7;
  const int xcd = orig & 7, lid = orig >> 3;
  const int wg = (xcd < r ? xcd * (q + 1) : r * (q + 1) + (xcd - r) * q) + lid;
  const int bx = wg % gridDim.x, by = wg / gridDim.x;

  const size_t brow = (size_t)by * 256;
  const size_t bcol = (size_t)bx * 256;
  const int kStart = (int)blockIdx.z * kLen;
  const int NT = kLen / 64;

  // staging addressing
  const int kbx = (lane & 7) ^ (lane >> 3);  // source 16B-group within 128B row
  const int rsub = lane >> 3;                // row within 8-row wave stripe
  const size_t strideK = (size_t)K * 128;    // 64 rows * K * 2B
  const char* gA0 = (const char*)A +
      ((brow + (size_t)(wid * 8 + rsub)) * (size_t)K + kStart + kbx * 8) * 2;
  const char* gB0 = (const char*)Bw +
      ((bcol + (size_t)(wid * 8 + rsub)) * (size_t)K + kStart + kbx * 8) * 2;
  const int dW = wid * 1024;

  // frag read offsets: row*128 + ((s*4 + (lane>>4)) ^ (lane&7)) * 16
  const int gx0 = (((lane >> 4) ^ (lane & 7))) * 16;
  const int gx1 = ((((lane >> 4) + 4) ^ (lane & 7))) * 16;
  const int arow = (wr * 128 + (lane & 15)) * 128;
  const int brw = 32768 + (wc * 64 + (lane & 15)) * 128;

  f32x4 acc[8][4] = {};

  // prologue: stage tile 0, drain, barrier
  STAGE(0);
  asm volatile("s_waitcnt vmcnt(0)" ::: "memory");
  __builtin_amdgcn_s_barrier();

  for (int T = 0; T < NT; ++T) {
    if (T + 1 < NT) STAGE(T + 1);

    const int sl = (T & 1) * SLOT;
    bf16x8 af[8], bfr[4];
    // ---- K-half 0
#pragma unroll
    for (int mf = 0; mf < 8; ++mf)
      af[mf] = *(const bf16x8*)(lds_raw + sl + arow + mf * 2048 + gx0);
#pragma unroll
    for (int nf = 0; nf < 4; ++nf)
      bfr[nf] = *(const bf16x8*)(lds_raw + sl + brw + nf * 2048 + gx0);
    __builtin_amdgcn_s_setprio(1);
#pragma unroll
    for (int mf = 0; mf < 8; ++mf)
#pragma unroll
      for (int nf = 0; nf < 4; ++nf)
        acc[mf][nf] =
            __builtin_amdgcn_mfma_f32_16x16x32_bf16(af[mf], bfr[nf], acc[mf][nf], 0, 0, 0);
    __builtin_amdgcn_s_setprio(0);
    // ---- K-half 1
#pragma unroll
    for (int mf = 0; mf < 8; ++mf)
      af[mf] = *(const bf16x8*)(lds_raw + sl + arow + mf * 2048 + gx1);
#pragma unroll
    for (int nf = 0; nf < 4; ++nf)
      bfr[nf] = *(const bf16x8*)(lds_raw + sl + brw + nf * 2048 + gx1);
    __builtin_amdgcn_s_setprio(1);
#pragma unroll
    for (int mf = 0; mf < 8; ++mf)
#pragma unroll
      for (int nf = 0; nf < 4; ++nf)
        acc[mf][nf] =
            __builtin_amdgcn_mfma_f32_16x16x32_bf16(af[mf], bfr[nf], acc[mf][nf], 0, 0, 0);
    __builtin_amdgcn_s_setprio(0);

    // one drain + barrier per K-64 tile (stage was issued a full tile ago)
    asm volatile("s_waitcnt vmcnt(0)" ::: "memory");
    asm volatile("s_waitcnt lgkmcnt(0)" ::: "memory");
    __builtin_amdgcn_s_barrier();
  }

  if constexpr (FUSE) {
    // ---- GLU + KAN-feature epilogue -> A3 plane-major (coalesced stores)
    float* gbuf = (float*)lds_raw;  // 16 slices x 16 rows x 128 pairs f32 = 128KB
#pragma unroll
    for (int mf = 0; mf < 8; ++mf) {
      const int s = wr * 8 + mf;
#pragma unroll
      for (int nf = 0; nf < 4; ++nf) {
#pragma unroll
        for (int rr = 0; rr < 4; ++rr) {
          float v = acc[mf][nf][rr];
          float w = __shfl_xor(v, 1, 64);
          if (!(lane & 1)) {
            const int r4 = (lane >> 4) * 4 + rr;
            const int ploc = wc * 32 + nf * 8 + ((lane & 14) >> 1);
            gbuf[s * 2048 + r4 * 128 + ploc] = v * w;
          }
        }
      }
    }
    __builtin_amdgcn_s_barrier();
    const int p2 = tid & 63;   // handles h-cols (bcol/2 + 2p2, +1)
    const int rb = tid >> 6;   // base row
    for (int k = 0; k < 32; ++k) {
      const int rr_ = rb + 8 * k;  // 0..255
      const int s = rr_ >> 4, rl = rr_ & 15;
      float g0 = gbuf[s * 2048 + rl * 128 + 2 * p2];
      float g1 = gbuf[s * 2048 + rl * 128 + 2 * p2 + 1];
      unsigned short h0[9], h1[9];
      kan_feat_u(g0, h0);
      kan_feat_u(g1, h1);
      // plane-major: dword (f, jpair) at f*2048 + bcol/4 + p2 (lanes coalesced)
      uint32_t* dst = (uint32_t*)(A3out + (brow + rr_) * (size_t)K3);
      const size_t pbase = (bcol >> 2) + p2;
#pragma unroll
      for (int f = 0; f < 9; ++f)
        dst[(size_t)f * 2048 + pbase] = (uint32_t)h0[f] | ((uint32_t)h1[f] << 16);
    }
  } else {
    // plain epilogue: C/D layout col=lane&15, row=(lane>>4)*4+r
#pragma unroll
    for (int mf = 0; mf < 8; ++mf)
#pragma unroll
      for (int nf = 0; nf < 4; ++nf) {
        const size_t r0 = brow + wr * 128 + mf * 16 + (lane >> 4) * 4;
        const size_t c0 = bcol + wc * 64 + nf * 16 + (lane & 15);
        const size_t M = (size_t)gridDim.y * 256;
        CT* C = Cp + (size_t)blockIdx.z * M * (size_t)N;
#pragma unroll
        for (int rr = 0; rr < 4; ++rr) {
          float v = acc[mf][nf][rr];
          if constexpr (std::is_same<CT, float>::value)
            C[(r0 + rr) * (size_t)N + c0] = v;
          else
            C[(r0 + rr) * (size_t)N + c0] = __float2bfloat16(v);
        }
      }
  }
}

// sum nslice split-K partials (float4-vectorized)
__global__ void reduceK(const float* __restrict__ P, float* __restrict__ out,
                        size_t quarter, int nslice) {
  size_t t = (size_t)blockIdx.x * blockDim.x + threadIdx.x;
  if (t >= quarter) return;
  const float4* p = (const float4*)P;
  float4 a = p[t];
  for (int s = 1; s < nslice; ++s) {
    float4 b = p[(size_t)s * quarter + t];
    a.x += b.x; a.y += b.y; a.z += b.z; a.w += b.w;
  }
  ((float4*)out)[t] = a;
}

// ---------------------------------------------------------------------------
extern "C" void kernel_launch(void* const* d_in, const int* in_sizes, int n_in,
                              void* d_out, int out_size, void* d_ws, size_t ws_size,
                              hipStream_t stream) {
  const float* x   = (const float*)d_in[0];
  const float* bw1 = (const float*)d_in[1];
  const float* sw1 = (const float*)d_in[2];
  const float* bw2 = (const float*)d_in[3];
  const float* sw2 = (const float*)d_in[4];
  const float* bw3 = (const float*)d_in[5];
  const float* sw3 = (const float*)d_in[6];
  float* out = (float*)d_out;
  char* ws = (char*)d_ws;

  const size_t W12_B  = (size_t)8192 * K1 * 2;   // 150,994,944
  const size_t A1_B   = (size_t)NTOK * K1 * 2;   //  75,497,472
  const size_t A3F_B  = (size_t)NTOK * K3 * 2;   // 301,989,888
  const size_t A3C_B  = (size_t)CHUNK * K3 * 2;  //  75,497,472
  const size_t HF32_B = (size_t)NTOK * 8192 * 4; // 134,217,728

  const bool fused = ws_size >= W12_B + A1_B + A3F_B;  // 528,482,304
  const bool hF32  = ws_size >= W12_B + A1_B + HF32_B; // 360,710,144 (fallback)

  __hip_bfloat16* W12 = (__hip_bfloat16*)(ws);
  __hip_bfloat16* A1  = (__hip_bfloat16*)(ws + W12_B);
  __hip_bfloat16* W3  = A1;  // A1 dead after GEMM1

  size_t pairs12 = (size_t)D_FF * D_MODEL / 2;
  int blocks12 = (int)((pairs12 + 255) / 256);
  size_t pairs3 = (size_t)D_MODEL * D_FF / 2;
  int blocks3 = (int)((pairs3 + 255) / 256);
  size_t pairsA1 = (size_t)NTOK * D_MODEL / 2;

  if (fused) {
    __hip_bfloat16* A3f = (__hip_bfloat16*)(ws + W12_B + A1_B);
    float*          Par = (float*)(ws);  // reuses W12 region after GEMM1

    pack_kan_w<<<blocks12, 256, 0, stream>>>(bw1, sw1, W12, K1, 10, 2, 0, pairs12);
    pack_kan_w<<<blocks12, 256, 0, stream>>>(bw2, sw2, W12, K1, 10, 2, 1, pairs12);
    build_a1<<<(int)((pairsA1 + 255) / 256), 256, 0, stream>>>(x, A1);
    gemm256<float, true><<<dim3(8192 / 256, NTOK / 256, 1), 512, 0, stream>>>(
        A1, W12, nullptr, 8192, K1, K1, A3f);
    pack_kan_w<<<blocks3, 256, 0, stream>>>(bw3, sw3, W3, K3, 12, 1, 0, pairs3);
    gemm256<float, false><<<dim3(D_MODEL / 256, NTOK / 256, SPLITKF), 512, 0, stream>>>(
        A3f, W3, Par, D_MODEL, K3, K3 / SPLITKF, nullptr);
    size_t quarter = (size_t)NTOK * D_MODEL / 4;
    reduceK<<<(int)((quarter + 255) / 256), 256, 0, stream>>>(Par, out, quarter, SPLITKF);
  } else {
    void*           Hv  = (void*)(ws + W12_B + A1_B);
    __hip_bfloat16* A3c = (__hip_bfloat16*)(ws);        // W12 dead after GEMM1
    float*          Par = (float*)(ws + A3C_B);

    pack_kan_w<<<blocks12, 256, 0, stream>>>(bw1, sw1, W12, K1, 10, 1, 0, pairs12);
    pack_kan_w<<<blocks12, 256, 0, stream>>>(bw2, sw2, W12, K1, 10, 1, 4096, pairs12);
    build_a1<<<(int)((pairsA1 + 255) / 256), 256, 0, stream>>>(x, A1);
    if (hF32)
      gemm256<float, false><<<dim3(8192 / 256, NTOK / 256, 1), 512, 0, stream>>>(
          A1, W12, (float*)Hv, 8192, K1, K1, nullptr);
    else
      gemm256<__hip_bfloat16, false><<<dim3(8192 / 256, NTOK / 256, 1), 512, 0, stream>>>(
          A1, W12, (__hip_bfloat16*)Hv, 8192, K1, K1, nullptr);
    pack_kan_w<<<blocks3, 256, 0, stream>>>(bw3, sw3, W3, K3, 12, 1, 0, pairs3);
    for (int c = 0; c < NTOK / CHUNK; ++c) {
      size_t pairsG = (size_t)CHUNK * D_FF / 2;
      int blocksG = (int)((pairsG + 255) / 256);
      if (hF32)
        glu_a3<float><<<blocksG, 256, 0, stream>>>(
            (const float*)Hv + (size_t)c * CHUNK * 8192, A3c);
      else
        glu_a3<__hip_bfloat16><<<blocksG, 256, 0, stream>>>(
            (const __hip_bfloat16*)Hv + (size_t)c * CHUNK * 8192, A3c);
      gemm256<float, false><<<dim3(D_MODEL / 256, CHUNK / 256, SPLITK2), 512, 0, stream>>>(
          A3c, W3, Par, D_MODEL, K3, K3 / SPLITK2, nullptr);
      size_t quarter = (size_t)CHUNK * D_MODEL / 4;
      reduceK<<<(int)((quarter + 255) / 256), 256, 0, stream>>>(
          Par, out + (size_t)c * CHUNK * D_MODEL, quarter, SPLITK2);
    }
  }
}

// Round 18
// 966.246 us; speedup vs baseline: 1.1942x; 1.0478x over previous
//
#include <hip/hip_runtime.h>
#include <hip/hip_bf16.h>
#include <cstdint>
#include <cstddef>
#include <type_traits>

// KAN GLU expert: h = kan(x;w1) * kan(x;w2); out = kan(h;w3)
// kan(x;W) == [silu(x_i), B0..B7(x_i)]_i @ [base_w | spline_w]^T
// -> bf16 MFMA GEMMs with K expanded 9x (plane-major K: k' = f*IN + j).
//
// R18: faithful 8-phase m201-style schedule on the R17 base.
// Geometry: 256x256 block, 8 waves (2Mx4N), wave tile 128x64, BK=64,
// 512 thr. LDS = 4 units U(d,h) 32KB each: A-half(16KB)+B-half(16KB);
// K-step k lives in dbuf d=k&1. Wave (wr,wc) reads only A-half(wr) and
// B-half(wc>>1). 8 phases per iteration (2 K-steps); each phase:
//   ds_read subtile | stage ONE operand-half (2 gload_lds) | barrier |
//   lgkmcnt(0) | 16 MFMA | [vmcnt(4) at P4/P8] | barrier
// Stage schedule (iter i, a=2i): P1/2:(a+1).A-lo/hi, P3/4:(a+2).B-lo/hi,
// P5/6:(a+2).A-lo/hi, P7/8:(a+3).B-lo/hi. vmcnt(4) keeps 2 half-tiles in
// flight across barriers (never drains in steady state). FIFO-verified:
// every consumer's data lands >=1 barrier before use; every overwrite is
// >=2 barriers after the victim's last lgkmcnt(0). Last iteration: skip
// P3-P8 stages, vmcnt(0) at P4. Prologue: 6 halves + vmcnt(4).
// Swizzle: physical 16B-group gp = gl ^ (row&7) (measured conflict-free).
// Fused path: GEMM1 epilogue does GLU (interleaved W12 rows, shfl_xor)
// + KAN features -> A3 (plane-major, coalesced). GEMM2 split-K=4.

#define D_MODEL 1024
#define D_FF    4096
#define NTOK    4096
#define NC      9
#define K1      (D_MODEL * NC)  // 9216
#define K3      (D_FF * NC)     // 36864
#define SPLITK2 16              // fallback chunked GEMM2
#define SPLITKF 4               // fused full GEMM2
#define CHUNK   1024

typedef __attribute__((ext_vector_type(8))) short bf16x8;
typedef __attribute__((ext_vector_type(4))) float f32x4;

#define AS1 __attribute__((address_space(1)))
#define AS3 __attribute__((address_space(3)))

__device__ __forceinline__ unsigned short bf16b(float f) {
  __hip_bfloat16 h = __float2bfloat16(f);
  return __builtin_bit_cast(unsigned short, h);
}
__device__ __forceinline__ uint32_t pk2(float a, float b) {
  return (uint32_t)bf16b(a) | ((uint32_t)bf16b(b) << 16);
}

// ---------------------------------------------------------------------------
// silu + 8 cubic B-spline bases on uniform grid t_m = 0.4*m - 2.2
// ---------------------------------------------------------------------------
__device__ __forceinline__ void kan_feat_u(float x, unsigned short* dst) {
  float s = x / (1.0f + __expf(-x));
  float B[11];
#pragma unroll
  for (int j = 0; j < 11; ++j) {
    float gj = -2.2f + 0.4f * j;
    B[j] = (x >= gj && x < gj + 0.4f) ? 1.0f : 0.0f;
  }
#pragma unroll
  for (int p = 1; p <= 3; ++p) {
    float inv = 1.0f / (0.4f * p);
#pragma unroll
    for (int i = 0; i + p < 11; ++i) {
      float gi = -2.2f + 0.4f * i;
      B[i] = (x - gi) * inv * B[i] + ((gi + 0.4f + 0.4f * p) - x) * inv * B[i + 1];
    }
  }
  dst[0] = bf16b(s);
#pragma unroll
  for (int c = 0; c < 8; ++c) dst[1 + c] = bf16b(B[c]);
}

// ---------------------------------------------------------------------------
// Pack weights, PLANE-MAJOR: W[row][f*IN + j]; 9 coalesced dword stores.
// dst row = o*rowMul + rowBase (rowMul=2 interleaves two layers).
// ---------------------------------------------------------------------------
__global__ void pack_kan_w(const float* __restrict__ bw, const float* __restrict__ sw,
                           __hip_bfloat16* __restrict__ W, int K, int inShift,
                           int rowMul, int rowBase, size_t totalPairs) {
  size_t t = (size_t)blockIdx.x * blockDim.x + threadIdx.x;
  if (t >= totalPairs) return;
  const int halfShift = inShift - 1;
  size_t o = t >> halfShift;
  size_t p = t & (((size_t)1 << halfShift) - 1);
  size_t e0 = (o << inShift) + 2 * p;
  float2 b = *(const float2*)(bw + e0);
  const float4* sp = (const float4*)(sw + e0 * 8);
  float4 s0 = sp[0], s1 = sp[1], s2 = sp[2], s3 = sp[3];
  const size_t HP = (size_t)1 << halfShift;
  uint32_t* dst = (uint32_t*)(W + (o * rowMul + rowBase) * (size_t)K);
  dst[p]          = pk2(b.x, b.y);
  dst[1 * HP + p] = pk2(s0.x, s2.x);
  dst[2 * HP + p] = pk2(s0.y, s2.y);
  dst[3 * HP + p] = pk2(s0.z, s2.z);
  dst[4 * HP + p] = pk2(s0.w, s2.w);
  dst[5 * HP + p] = pk2(s1.x, s3.x);
  dst[6 * HP + p] = pk2(s1.y, s3.y);
  dst[7 * HP + p] = pk2(s1.z, s3.z);
  dst[8 * HP + p] = pk2(s1.w, s3.w);
}

// A1 plane-major: A1[n][f*1024 + i]
__global__ void build_a1(const float* __restrict__ x, __hip_bfloat16* __restrict__ A1) {
  size_t t = (size_t)blockIdx.x * blockDim.x + threadIdx.x;
  if (t >= (size_t)NTOK * D_MODEL / 2) return;
  size_t n = t >> 9;
  size_t p = t & 511;
  float2 xv = *(const float2*)(x + n * D_MODEL + 2 * p);
  unsigned short h0[9], h1[9];
  kan_feat_u(xv.x, h0);
  kan_feat_u(xv.y, h1);
  uint32_t* dst = (uint32_t*)(A1 + n * (size_t)K1);
#pragma unroll
  for (int f = 0; f < 9; ++f)
    dst[(size_t)f * 512 + p] = (uint32_t)h0[f] | ((uint32_t)h1[f] << 16);
}

// fallback only: h = Hc[:, :4096] * Hc[:, 4096:]; A3 plane-major
template <typename HT>
__global__ void glu_a3(const HT* __restrict__ Hc, __hip_bfloat16* __restrict__ A3c) {
  size_t t = (size_t)blockIdx.x * blockDim.x + threadIdx.x;
  if (t >= (size_t)CHUNK * D_FF / 2) return;
  size_t n = t >> 11;
  size_t p = t & 2047;
  float a0, a1, c0, c1;
  if constexpr (std::is_same<HT, float>::value) {
    float2 u = *(const float2*)(Hc + n * 8192 + 2 * p);
    float2 v = *(const float2*)(Hc + n * 8192 + 4096 + 2 * p);
    a0 = u.x; a1 = u.y; c0 = v.x; c1 = v.y;
  } else {
    a0 = __bfloat162float(Hc[n * 8192 + 2 * p]);
    a1 = __bfloat162float(Hc[n * 8192 + 2 * p + 1]);
    c0 = __bfloat162float(Hc[n * 8192 + 4096 + 2 * p]);
    c1 = __bfloat162float(Hc[n * 8192 + 4096 + 2 * p + 1]);
  }
  unsigned short h0[9], h1[9];
  kan_feat_u(a0 * c0, h0);
  kan_feat_u(a1 * c1, h1);
  uint32_t* dst = (uint32_t*)(A3c + n * (size_t)K3);
#pragma unroll
  for (int f = 0; f < 9; ++f)
    dst[(size_t)f * 2048 + p] = (uint32_t)h0[f] | ((uint32_t)h1[f] << 16);
}

// ---------------------------------------------------------------------------
// 8-phase GEMM helpers
// ---------------------------------------------------------------------------
#define LDSA(D, MF, GX) \
  (*(const bf16x8*)(lds_raw + (D)*65536 + aoffH + (MF)*2048 + (GX)))
#define LDSB(D, NF, GX) \
  (*(const bf16x8*)(lds_raw + (D)*65536 + boffH + (NF)*2048 + (GX)))

// stage operand-half: 2 gload_lds (rows l*64+(tid>>3) of half h, K-step k)
#define STAGE_A(KK, H)                                                                   \
  {                                                                                      \
    const size_t _s = (size_t)(H) * 128 * strideRow + (size_t)(KK) * 128;                \
    const int _d = (((KK) & 1) * 65536) + ((H) * 32768) + dT;                            \
    __builtin_amdgcn_global_load_lds((const AS1 void*)(gAb + _s),                        \
                                     (AS3 void*)(lds_raw + _d), 16, 0, 0);               \
    __builtin_amdgcn_global_load_lds((const AS1 void*)(gAb + _s + 64 * strideRow),       \
                                     (AS3 void*)(lds_raw + _d + 8192), 16, 0, 0);        \
  }
#define STAGE_B(KK, H)                                                                   \
  {                                                                                      \
    const size_t _s = (size_t)(H) * 128 * strideRow + (size_t)(KK) * 128;                \
    const int _d = (((KK) & 1) * 65536) + ((H) * 32768) + 16384 + dT;                    \
    __builtin_amdgcn_global_load_lds((const AS1 void*)(gBb + _s),                        \
                                     (AS3 void*)(lds_raw + _d), 16, 0, 0);               \
    __builtin_amdgcn_global_load_lds((const AS1 void*)(gBb + _s + 64 * strideRow),       \
                                     (AS3 void*)(lds_raw + _d + 8192), 16, 0, 0);        \
  }

#define MF16(P)                                                                          \
  __builtin_amdgcn_s_setprio(1);                                                         \
  _Pragma("unroll") for (int _m = 0; _m < 2; ++_m)                                       \
      _Pragma("unroll") for (int _n = 0; _n < 4; ++_n) {                                 \
    acc[2 * (P) + _m][_n] = __builtin_amdgcn_mfma_f32_16x16x32_bf16(                     \
        af[_m][0], bfr[_n][0], acc[2 * (P) + _m][_n], 0, 0, 0);                          \
    acc[2 * (P) + _m][_n] = __builtin_amdgcn_mfma_f32_16x16x32_bf16(                     \
        af[_m][1], bfr[_n][1], acc[2 * (P) + _m][_n], 0, 0, 0);                          \
  }                                                                                      \
  __builtin_amdgcn_s_setprio(0);

// phase p=0 of a K-step: read all B-frags + af rows 0,1
#define PH0(D, STG, WT)                                                                  \
  {                                                                                      \
    _Pragma("unroll") for (int _n = 0; _n < 4; ++_n) {                                   \
      bfr[_n][0] = LDSB(D, _n, gx0);                                                     \
      bfr[_n][1] = LDSB(D, _n, gx1);                                                     \
    }                                                                                    \
    af[0][0] = LDSA(D, 0, gx0); af[0][1] = LDSA(D, 0, gx1);                              \
    af[1][0] = LDSA(D, 1, gx0); af[1][1] = LDSA(D, 1, gx1);                              \
    STG;                                                                                 \
    __builtin_amdgcn_s_barrier();                                                        \
    asm volatile("s_waitcnt lgkmcnt(0)" ::: "memory");                                   \
    __builtin_amdgcn_sched_barrier(0);                                                   \
    MF16(0);                                                                             \
    WT;                                                                                  \
    __builtin_amdgcn_s_barrier();                                                        \
  }
// phases p=1..3: read af rows 2p, 2p+1 only
#define PHN(D, P, STG, WT)                                                               \
  {                                                                                      \
    af[0][0] = LDSA(D, 2 * (P), gx0);     af[0][1] = LDSA(D, 2 * (P), gx1);              \
    af[1][0] = LDSA(D, 2 * (P) + 1, gx0); af[1][1] = LDSA(D, 2 * (P) + 1, gx1);          \
    STG;                                                                                 \
    __builtin_amdgcn_s_barrier();                                                        \
    asm volatile("s_waitcnt lgkmcnt(0)" ::: "memory");                                   \
    __builtin_amdgcn_sched_barrier(0);                                                   \
    MF16(P);                                                                             \
    WT;                                                                                  \
    __builtin_amdgcn_s_barrier();                                                        \
  }

#define VM4 asm volatile("s_waitcnt vmcnt(4)" ::: "memory")
#define VM0 asm volatile("s_waitcnt vmcnt(0)" ::: "memory")

template <typename CT, bool FUSE>
__global__ __launch_bounds__(512, 2) void gemm256(
    const __hip_bfloat16* __restrict__ A, const __hip_bfloat16* __restrict__ Bw,
    CT* __restrict__ Cp, int N, int K, int kLen,
    __hip_bfloat16* __restrict__ A3out) {
  __shared__ __align__(16) char lds_raw[131072];  // 4 units x 32KB

  const int tid = threadIdx.x;
  const int wid = tid >> 6, lane = tid & 63;
  const int wr = wid >> 2, wc = wid & 3;  // 2M x 4N waves, 128x64 tiles

  // bijective XCD swizzle (T1); all grids have nwg % 8 == 0
  const int nwg = gridDim.x * gridDim.y;
  const int orig = blockIdx.y * gridDim.x + blockIdx.x;
  const int q = nwg >> 3, r = nwg & 7;
  const int xcd = orig & 7, lid = orig >> 3;
  const int wg = (xcd < r ? xcd * (q + 1) : r * (q + 1) + (xcd - r) * q) + lid;
  const int bx = wg % gridDim.x, by = wg / gridDim.x;

  const size_t brow = (size_t)by * 256;
  const size_t bcol = (size_t)bx * 256;
  const int kStart = (int)blockIdx.z * kLen;
  const int NT = kLen / 64;  // even (144 for both GEMMs)

  // staging addressing (512 thr; operand-half = 128 rows x 128B, 2 loads)
  const int kbx = (tid & 7) ^ ((tid >> 3) & 7);  // pre-swizzled source group
  const size_t strideRow = (size_t)K * 2;        // row stride, bytes
  const char* gAb = (const char*)A + ((brow + (size_t)(tid >> 3)) * (size_t)K + kStart) * 2 + kbx * 16;
  const char* gBb = (const char*)Bw + ((bcol + (size_t)(tid >> 3)) * (size_t)K + kStart) * 2 + kbx * 16;
  const int dT = tid * 16;

  // frag read offsets: physical group = (s ^ (row&7)); row&7 == lane&7
  const int gx0 = (((lane >> 4) ^ (lane & 7))) * 16;
  const int gx1 = ((((lane >> 4) + 4) ^ (lane & 7))) * 16;
  const int aoffH = wr * 32768 + (lane & 15) * 128;
  const int boffH = (wc >> 1) * 32768 + 16384 + ((wc & 1) * 64 + (lane & 15)) * 128;

  f32x4 acc[8][4] = {};
  bf16x8 af[2][2], bfr[4][2];

  // prologue: stage 0.B-lo/hi, 0.A-lo/hi, 1.B-lo/hi; keep 1.B in flight
  STAGE_B(0, 0); STAGE_B(0, 1);
  STAGE_A(0, 0); STAGE_A(0, 1);
  STAGE_B(1, 0); STAGE_B(1, 1);
  VM4;
  __builtin_amdgcn_s_barrier();

  for (int i = 0; i < NT / 2; ++i) {
    const int a = 2 * i;
    const bool nl = (i != NT / 2 - 1);  // not last iteration
    // K-step a (dbuf 0)
    PH0(0, STAGE_A(a + 1, 0), );
    PHN(0, 1, STAGE_A(a + 1, 1), );
    PHN(0, 2, if (nl) STAGE_B(a + 2, 0), );
    PHN(0, 3, if (nl) STAGE_B(a + 2, 1), if (nl) { VM4; } else { VM0; });
    // K-step a+1 (dbuf 1)
    PH0(1, if (nl) STAGE_A(a + 2, 0), );
    PHN(1, 1, if (nl) STAGE_A(a + 2, 1), );
    PHN(1, 2, if (nl) STAGE_B(a + 3, 0), );
    PHN(1, 3, if (nl) STAGE_B(a + 3, 1), if (nl) { VM4; } else { VM0; });
  }

  if constexpr (FUSE) {
    // ---- GLU + KAN-feature epilogue -> A3 plane-major (coalesced stores)
    float* gbuf = (float*)lds_raw;  // 16 slices x 16 rows x 128 pairs f32 = 128KB
#pragma unroll
    for (int mf = 0; mf < 8; ++mf) {
      const int s = wr * 8 + mf;
#pragma unroll
      for (int nf = 0; nf < 4; ++nf) {
#pragma unroll
        for (int rr = 0; rr < 4; ++rr) {
          float v = acc[mf][nf][rr];
          float w = __shfl_xor(v, 1, 64);
          if (!(lane & 1)) {
            const int r4 = (lane >> 4) * 4 + rr;
            const int ploc = wc * 32 + nf * 8 + ((lane & 14) >> 1);
            gbuf[s * 2048 + r4 * 128 + ploc] = v * w;
          }
        }
      }
    }
    __builtin_amdgcn_s_barrier();
    const int p2 = tid & 63;
    const int rb = tid >> 6;
    for (int k = 0; k < 32; ++k) {
      const int rr_ = rb + 8 * k;
      const int s = rr_ >> 4, rl = rr_ & 15;
      float g0 = gbuf[s * 2048 + rl * 128 + 2 * p2];
      float g1 = gbuf[s * 2048 + rl * 128 + 2 * p2 + 1];
      unsigned short h0[9], h1[9];
      kan_feat_u(g0, h0);
      kan_feat_u(g1, h1);
      uint32_t* dst = (uint32_t*)(A3out + (brow + rr_) * (size_t)K3);
      const size_t pbase = (bcol >> 2) + p2;
#pragma unroll
      for (int f = 0; f < 9; ++f)
        dst[(size_t)f * 2048 + pbase] = (uint32_t)h0[f] | ((uint32_t)h1[f] << 16);
    }
  } else {
    // plain epilogue: C/D layout col=lane&15, row=(lane>>4)*4+r
#pragma unroll
    for (int mf = 0; mf < 8; ++mf)
#pragma unroll
      for (int nf = 0; nf < 4; ++nf) {
        const size_t r0 = brow + wr * 128 + mf * 16 + (lane >> 4) * 4;
        const size_t c0 = bcol + wc * 64 + nf * 16 + (lane & 15);
        const size_t M = (size_t)gridDim.y * 256;
        CT* C = Cp + (size_t)blockIdx.z * M * (size_t)N;
#pragma unroll
        for (int rr = 0; rr < 4; ++rr) {
          float v = acc[mf][nf][rr];
          if constexpr (std::is_same<CT, float>::value)
            C[(r0 + rr) * (size_t)N + c0] = v;
          else
            C[(r0 + rr) * (size_t)N + c0] = __float2bfloat16(v);
        }
      }
  }
}

// sum nslice split-K partials (float4-vectorized)
__global__ void reduceK(const float* __restrict__ P, float* __restrict__ out,
                        size_t quarter, int nslice) {
  size_t t = (size_t)blockIdx.x * blockDim.x + threadIdx.x;
  if (t >= quarter) return;
  const float4* p = (const float4*)P;
  float4 a = p[t];
  for (int s = 1; s < nslice; ++s) {
    float4 b = p[(size_t)s * quarter + t];
    a.x += b.x; a.y += b.y; a.z += b.z; a.w += b.w;
  }
  ((float4*)out)[t] = a;
}

// ---------------------------------------------------------------------------
extern "C" void kernel_launch(void* const* d_in, const int* in_sizes, int n_in,
                              void* d_out, int out_size, void* d_ws, size_t ws_size,
                              hipStream_t stream) {
  const float* x   = (const float*)d_in[0];
  const float* bw1 = (const float*)d_in[1];
  const float* sw1 = (const float*)d_in[2];
  const float* bw2 = (const float*)d_in[3];
  const float* sw2 = (const float*)d_in[4];
  const float* bw3 = (const float*)d_in[5];
  const float* sw3 = (const float*)d_in[6];
  float* out = (float*)d_out;
  char* ws = (char*)d_ws;

  const size_t W12_B  = (size_t)8192 * K1 * 2;   // 150,994,944
  const size_t A1_B   = (size_t)NTOK * K1 * 2;   //  75,497,472
  const size_t A3F_B  = (size_t)NTOK * K3 * 2;   // 301,989,888
  const size_t A3C_B  = (size_t)CHUNK * K3 * 2;  //  75,497,472
  const size_t HF32_B = (size_t)NTOK * 8192 * 4; // 134,217,728

  const bool fused = ws_size >= W12_B + A1_B + A3F_B;  // 528,482,304
  const bool hF32  = ws_size >= W12_B + A1_B + HF32_B; // 360,710,144 (fallback)

  __hip_bfloat16* W12 = (__hip_bfloat16*)(ws);
  __hip_bfloat16* A1  = (__hip_bfloat16*)(ws + W12_B);
  __hip_bfloat16* W3  = A1;  // A1 dead after GEMM1

  size_t pairs12 = (size_t)D_FF * D_MODEL / 2;
  int blocks12 = (int)((pairs12 + 255) / 256);
  size_t pairs3 = (size_t)D_MODEL * D_FF / 2;
  int blocks3 = (int)((pairs3 + 255) / 256);
  size_t pairsA1 = (size_t)NTOK * D_MODEL / 2;

  if (fused) {
    __hip_bfloat16* A3f = (__hip_bfloat16*)(ws + W12_B + A1_B);
    float*          Par = (float*)(ws);  // reuses W12 region after GEMM1

    pack_kan_w<<<blocks12, 256, 0, stream>>>(bw1, sw1, W12, K1, 10, 2, 0, pairs12);
    pack_kan_w<<<blocks12, 256, 0, stream>>>(bw2, sw2, W12, K1, 10, 2, 1, pairs12);
    build_a1<<<(int)((pairsA1 + 255) / 256), 256, 0, stream>>>(x, A1);
    gemm256<float, true><<<dim3(8192 / 256, NTOK / 256, 1), 512, 0, stream>>>(
        A1, W12, nullptr, 8192, K1, K1, A3f);
    pack_kan_w<<<blocks3, 256, 0, stream>>>(bw3, sw3, W3, K3, 12, 1, 0, pairs3);
    gemm256<float, false><<<dim3(D_MODEL / 256, NTOK / 256, SPLITKF), 512, 0, stream>>>(
        A3f, W3, Par, D_MODEL, K3, K3 / SPLITKF, nullptr);
    size_t quarter = (size_t)NTOK * D_MODEL / 4;
    reduceK<<<(int)((quarter + 255) / 256), 256, 0, stream>>>(Par, out, quarter, SPLITKF);
  } else {
    void*           Hv  = (void*)(ws + W12_B + A1_B);
    __hip_bfloat16* A3c = (__hip_bfloat16*)(ws);        // W12 dead after GEMM1
    float*          Par = (float*)(ws + A3C_B);

    pack_kan_w<<<blocks12, 256, 0, stream>>>(bw1, sw1, W12, K1, 10, 1, 0, pairs12);
    pack_kan_w<<<blocks12, 256, 0, stream>>>(bw2, sw2, W12, K1, 10, 1, 4096, pairs12);
    build_a1<<<(int)((pairsA1 + 255) / 256), 256, 0, stream>>>(x, A1);
    if (hF32)
      gemm256<float, false><<<dim3(8192 / 256, NTOK / 256, 1), 512, 0, stream>>>(
          A1, W12, (float*)Hv, 8192, K1, K1, nullptr);
    else
      gemm256<__hip_bfloat16, false><<<dim3(8192 / 256, NTOK / 256, 1), 512, 0, stream>>>(
          A1, W12, (__hip_bfloat16*)Hv, 8192, K1, K1, nullptr);
    pack_kan_w<<<blocks3, 256, 0, stream>>>(bw3, sw3, W3, K3, 12, 1, 0, pairs3);
    for (int c = 0; c < NTOK / CHUNK; ++c) {
      size_t pairsG = (size_t)CHUNK * D_FF / 2;
      int blocksG = (int)((pairsG + 255) / 256);
      if (hF32)
        glu_a3<float><<<blocksG, 256, 0, stream>>>(
            (const float*)Hv + (size_t)c * CHUNK * 8192, A3c);
      else
        glu_a3<__hip_bfloat16><<<blocksG, 256, 0, stream>>>(
            (const __hip_bfloat16*)Hv + (size_t)c * CHUNK * 8192, A3c);
      gemm256<float, false><<<dim3(D_MODEL / 256, CHUNK / 256, SPLITK2), 512, 0, stream>>>(
          A3c, W3, Par, D_MODEL, K3, K3 / SPLITK2, nullptr);
      size_t quarter = (size_t)CHUNK * D_MODEL / 4;
      reduceK<<<(int)((quarter + 255) / 256), 256, 0, stream>>>(
          Par, out + (size_t)c * CHUNK * D_MODEL, quarter, SPLITK2);
    }
  }
}

// Round 19
// 961.909 us; speedup vs baseline: 1.1996x; 1.0045x over previous
//
#include <hip/hip_runtime.h>
#include <hip/hip_bf16.h>
#include <cstdint>
#include <cstddef>
#include <type_traits>

// KAN GLU expert: h = kan(x;w1) * kan(x;w2); out = kan(h;w3)
// kan(x;W) == [silu(x_i), B0..B7(x_i)]_i @ [base_w | spline_w]^T
// -> bf16 MFMA GEMMs with K expanded 9x (plane-major K: k' = f*IN + j).
//
// R19 = R18 8-phase schedule + counted lgkmcnt inside phases:
// each phase's ds_reads are split lo-k / hi-k (order pinned by
// sched_barrier(0)); after the barrier, lgkmcnt(6|2) releases the 8 lo-MFMAs
// while the hi-group reads drain beneath them, then lgkmcnt(0) + 8 hi-MFMAs.
// Everything else identical to R18 (see that round's FIFO/race proof).

#define D_MODEL 1024
#define D_FF    4096
#define NTOK    4096
#define NC      9
#define K1      (D_MODEL * NC)  // 9216
#define K3      (D_FF * NC)     // 36864
#define SPLITK2 16              // fallback chunked GEMM2
#define SPLITKF 4               // fused full GEMM2
#define CHUNK   1024

typedef __attribute__((ext_vector_type(8))) short bf16x8;
typedef __attribute__((ext_vector_type(4))) float f32x4;

#define AS1 __attribute__((address_space(1)))
#define AS3 __attribute__((address_space(3)))

__device__ __forceinline__ unsigned short bf16b(float f) {
  __hip_bfloat16 h = __float2bfloat16(f);
  return __builtin_bit_cast(unsigned short, h);
}
__device__ __forceinline__ uint32_t pk2(float a, float b) {
  return (uint32_t)bf16b(a) | ((uint32_t)bf16b(b) << 16);
}

// ---------------------------------------------------------------------------
// silu + 8 cubic B-spline bases on uniform grid t_m = 0.4*m - 2.2
// ---------------------------------------------------------------------------
__device__ __forceinline__ void kan_feat_u(float x, unsigned short* dst) {
  float s = x / (1.0f + __expf(-x));
  float B[11];
#pragma unroll
  for (int j = 0; j < 11; ++j) {
    float gj = -2.2f + 0.4f * j;
    B[j] = (x >= gj && x < gj + 0.4f) ? 1.0f : 0.0f;
  }
#pragma unroll
  for (int p = 1; p <= 3; ++p) {
    float inv = 1.0f / (0.4f * p);
#pragma unroll
    for (int i = 0; i + p < 11; ++i) {
      float gi = -2.2f + 0.4f * i;
      B[i] = (x - gi) * inv * B[i] + ((gi + 0.4f + 0.4f * p) - x) * inv * B[i + 1];
    }
  }
  dst[0] = bf16b(s);
#pragma unroll
  for (int c = 0; c < 8; ++c) dst[1 + c] = bf16b(B[c]);
}

// ---------------------------------------------------------------------------
// Pack weights, PLANE-MAJOR: W[row][f*IN + j]; 9 coalesced dword stores.
// ---------------------------------------------------------------------------
__global__ void pack_kan_w(const float* __restrict__ bw, const float* __restrict__ sw,
                           __hip_bfloat16* __restrict__ W, int K, int inShift,
                           int rowMul, int rowBase, size_t totalPairs) {
  size_t t = (size_t)blockIdx.x * blockDim.x + threadIdx.x;
  if (t >= totalPairs) return;
  const int halfShift = inShift - 1;
  size_t o = t >> halfShift;
  size_t p = t & (((size_t)1 << halfShift) - 1);
  size_t e0 = (o << inShift) + 2 * p;
  float2 b = *(const float2*)(bw + e0);
  const float4* sp = (const float4*)(sw + e0 * 8);
  float4 s0 = sp[0], s1 = sp[1], s2 = sp[2], s3 = sp[3];
  const size_t HP = (size_t)1 << halfShift;
  uint32_t* dst = (uint32_t*)(W + (o * rowMul + rowBase) * (size_t)K);
  dst[p]          = pk2(b.x, b.y);
  dst[1 * HP + p] = pk2(s0.x, s2.x);
  dst[2 * HP + p] = pk2(s0.y, s2.y);
  dst[3 * HP + p] = pk2(s0.z, s2.z);
  dst[4 * HP + p] = pk2(s0.w, s2.w);
  dst[5 * HP + p] = pk2(s1.x, s3.x);
  dst[6 * HP + p] = pk2(s1.y, s3.y);
  dst[7 * HP + p] = pk2(s1.z, s3.z);
  dst[8 * HP + p] = pk2(s1.w, s3.w);
}

// A1 plane-major: A1[n][f*1024 + i]
__global__ void build_a1(const float* __restrict__ x, __hip_bfloat16* __restrict__ A1) {
  size_t t = (size_t)blockIdx.x * blockDim.x + threadIdx.x;
  if (t >= (size_t)NTOK * D_MODEL / 2) return;
  size_t n = t >> 9;
  size_t p = t & 511;
  float2 xv = *(const float2*)(x + n * D_MODEL + 2 * p);
  unsigned short h0[9], h1[9];
  kan_feat_u(xv.x, h0);
  kan_feat_u(xv.y, h1);
  uint32_t* dst = (uint32_t*)(A1 + n * (size_t)K1);
#pragma unroll
  for (int f = 0; f < 9; ++f)
    dst[(size_t)f * 512 + p] = (uint32_t)h0[f] | ((uint32_t)h1[f] << 16);
}

// fallback only: h = Hc[:, :4096] * Hc[:, 4096:]; A3 plane-major
template <typename HT>
__global__ void glu_a3(const HT* __restrict__ Hc, __hip_bfloat16* __restrict__ A3c) {
  size_t t = (size_t)blockIdx.x * blockDim.x + threadIdx.x;
  if (t >= (size_t)CHUNK * D_FF / 2) return;
  size_t n = t >> 11;
  size_t p = t & 2047;
  float a0, a1, c0, c1;
  if constexpr (std::is_same<HT, float>::value) {
    float2 u = *(const float2*)(Hc + n * 8192 + 2 * p);
    float2 v = *(const float2*)(Hc + n * 8192 + 4096 + 2 * p);
    a0 = u.x; a1 = u.y; c0 = v.x; c1 = v.y;
  } else {
    a0 = __bfloat162float(Hc[n * 8192 + 2 * p]);
    a1 = __bfloat162float(Hc[n * 8192 + 2 * p + 1]);
    c0 = __bfloat162float(Hc[n * 8192 + 4096 + 2 * p]);
    c1 = __bfloat162float(Hc[n * 8192 + 4096 + 2 * p + 1]);
  }
  unsigned short h0[9], h1[9];
  kan_feat_u(a0 * c0, h0);
  kan_feat_u(a1 * c1, h1);
  uint32_t* dst = (uint32_t*)(A3c + n * (size_t)K3);
#pragma unroll
  for (int f = 0; f < 9; ++f)
    dst[(size_t)f * 2048 + p] = (uint32_t)h0[f] | ((uint32_t)h1[f] << 16);
}

// ---------------------------------------------------------------------------
// 8-phase GEMM helpers
// ---------------------------------------------------------------------------
#define LDSA(D, MF, GX) \
  (*(const bf16x8*)(lds_raw + (D)*65536 + aoffH + (MF)*2048 + (GX)))
#define LDSB(D, NF, GX) \
  (*(const bf16x8*)(lds_raw + (D)*65536 + boffH + (NF)*2048 + (GX)))

#define STAGE_A(KK, H)                                                                   \
  {                                                                                      \
    const size_t _s = (size_t)(H) * 128 * strideRow + (size_t)(KK) * 128;                \
    const int _d = (((KK) & 1) * 65536) + ((H) * 32768) + dT;                            \
    __builtin_amdgcn_global_load_lds((const AS1 void*)(gAb + _s),                        \
                                     (AS3 void*)(lds_raw + _d), 16, 0, 0);               \
    __builtin_amdgcn_global_load_lds((const AS1 void*)(gAb + _s + 64 * strideRow),       \
                                     (AS3 void*)(lds_raw + _d + 8192), 16, 0, 0);        \
  }
#define STAGE_B(KK, H)                                                                   \
  {                                                                                      \
    const size_t _s = (size_t)(H) * 128 * strideRow + (size_t)(KK) * 128;                \
    const int _d = (((KK) & 1) * 65536) + ((H) * 32768) + 16384 + dT;                    \
    __builtin_amdgcn_global_load_lds((const AS1 void*)(gBb + _s),                        \
                                     (AS3 void*)(lds_raw + _d), 16, 0, 0);               \
    __builtin_amdgcn_global_load_lds((const AS1 void*)(gBb + _s + 64 * strideRow),       \
                                     (AS3 void*)(lds_raw + _d + 8192), 16, 0, 0);        \
  }

#define SB __builtin_amdgcn_sched_barrier(0)
#define LGKM(N) asm volatile("s_waitcnt lgkmcnt(" #N ")" ::: "memory")

// 8 MFMAs on k-half H of acc rows 2P,2P+1
#define MF8(P, H)                                                                        \
  _Pragma("unroll") for (int _m = 0; _m < 2; ++_m)                                       \
      _Pragma("unroll") for (int _n = 0; _n < 4; ++_n)                                   \
          acc[2 * (P) + _m][_n] = __builtin_amdgcn_mfma_f32_16x16x32_bf16(               \
              af[_m][H], bfr[_n][H], acc[2 * (P) + _m][_n], 0, 0, 0);

// phase p=0: read all B-frags + af rows 0,1 (lo group first, then hi group)
#define PH0(D, STG, WT)                                                                  \
  {                                                                                      \
    af[0][0] = LDSA(D, 0, gx0);                                                          \
    af[1][0] = LDSA(D, 1, gx0);                                                          \
    _Pragma("unroll") for (int _n = 0; _n < 4; ++_n) bfr[_n][0] = LDSB(D, _n, gx0);      \
    SB;                                                                                  \
    af[0][1] = LDSA(D, 0, gx1);                                                          \
    af[1][1] = LDSA(D, 1, gx1);                                                          \
    _Pragma("unroll") for (int _n = 0; _n < 4; ++_n) bfr[_n][1] = LDSB(D, _n, gx1);      \
    STG;                                                                                 \
    __builtin_amdgcn_s_barrier();                                                        \
    LGKM(6);                                                                             \
    SB;                                                                                  \
    __builtin_amdgcn_s_setprio(1);                                                       \
    MF8(0, 0);                                                                           \
    LGKM(0);                                                                             \
    SB;                                                                                  \
    MF8(0, 1);                                                                           \
    __builtin_amdgcn_s_setprio(0);                                                       \
    WT;                                                                                  \
    __builtin_amdgcn_s_barrier();                                                        \
  }
// phases p=1..3: read af rows 2p, 2p+1 only
#define PHN(D, P, STG, WT)                                                               \
  {                                                                                      \
    af[0][0] = LDSA(D, 2 * (P), gx0);                                                    \
    af[1][0] = LDSA(D, 2 * (P) + 1, gx0);                                                \
    SB;                                                                                  \
    af[0][1] = LDSA(D, 2 * (P), gx1);                                                    \
    af[1][1] = LDSA(D, 2 * (P) + 1, gx1);                                                \
    STG;                                                                                 \
    __builtin_amdgcn_s_barrier();                                                        \
    LGKM(2);                                                                             \
    SB;                                                                                  \
    __builtin_amdgcn_s_setprio(1);                                                       \
    MF8(P, 0);                                                                           \
    LGKM(0);                                                                             \
    SB;                                                                                  \
    MF8(P, 1);                                                                           \
    __builtin_amdgcn_s_setprio(0);                                                       \
    WT;                                                                                  \
    __builtin_amdgcn_s_barrier();                                                        \
  }

#define VM4 asm volatile("s_waitcnt vmcnt(4)" ::: "memory")
#define VM0 asm volatile("s_waitcnt vmcnt(0)" ::: "memory")

template <typename CT, bool FUSE>
__global__ __launch_bounds__(512, 2) void gemm256(
    const __hip_bfloat16* __restrict__ A, const __hip_bfloat16* __restrict__ Bw,
    CT* __restrict__ Cp, int N, int K, int kLen,
    __hip_bfloat16* __restrict__ A3out) {
  __shared__ __align__(16) char lds_raw[131072];  // 4 units x 32KB

  const int tid = threadIdx.x;
  const int wid = tid >> 6, lane = tid & 63;
  const int wr = wid >> 2, wc = wid & 3;  // 2M x 4N waves, 128x64 tiles

  // bijective XCD swizzle (T1); all grids have nwg % 8 == 0
  const int nwg = gridDim.x * gridDim.y;
  const int orig = blockIdx.y * gridDim.x + blockIdx.x;
  const int q = nwg >> 3, r = nwg & 7;
  const int xcd = orig & 7, lid = orig >> 3;
  const int wg = (xcd < r ? xcd * (q + 1) : r * (q + 1) + (xcd - r) * q) + lid;
  const int bx = wg % gridDim.x, by = wg / gridDim.x;

  const size_t brow = (size_t)by * 256;
  const size_t bcol = (size_t)bx * 256;
  const int kStart = (int)blockIdx.z * kLen;
  const int NT = kLen / 64;  // even (144 for both GEMMs)

  // staging addressing (512 thr; operand-half = 128 rows x 128B, 2 loads)
  const int kbx = (tid & 7) ^ ((tid >> 3) & 7);  // pre-swizzled source group
  const size_t strideRow = (size_t)K * 2;        // row stride, bytes
  const char* gAb = (const char*)A + ((brow + (size_t)(tid >> 3)) * (size_t)K + kStart) * 2 + kbx * 16;
  const char* gBb = (const char*)Bw + ((bcol + (size_t)(tid >> 3)) * (size_t)K + kStart) * 2 + kbx * 16;
  const int dT = tid * 16;

  // frag read offsets: physical group = (s ^ (row&7)); row&7 == lane&7
  const int gx0 = (((lane >> 4) ^ (lane & 7))) * 16;
  const int gx1 = ((((lane >> 4) + 4) ^ (lane & 7))) * 16;
  const int aoffH = wr * 32768 + (lane & 15) * 128;
  const int boffH = (wc >> 1) * 32768 + 16384 + ((wc & 1) * 64 + (lane & 15)) * 128;

  f32x4 acc[8][4] = {};
  bf16x8 af[2][2], bfr[4][2];

  // prologue: stage 0.B-lo/hi, 0.A-lo/hi, 1.B-lo/hi; keep 1.B in flight
  STAGE_B(0, 0); STAGE_B(0, 1);
  STAGE_A(0, 0); STAGE_A(0, 1);
  STAGE_B(1, 0); STAGE_B(1, 1);
  VM4;
  __builtin_amdgcn_s_barrier();

  for (int i = 0; i < NT / 2; ++i) {
    const int a = 2 * i;
    const bool nl = (i != NT / 2 - 1);  // not last iteration
    // K-step a (dbuf 0)
    PH0(0, STAGE_A(a + 1, 0), );
    PHN(0, 1, STAGE_A(a + 1, 1), );
    PHN(0, 2, if (nl) STAGE_B(a + 2, 0), );
    PHN(0, 3, if (nl) STAGE_B(a + 2, 1), if (nl) { VM4; } else { VM0; });
    // K-step a+1 (dbuf 1)
    PH0(1, if (nl) STAGE_A(a + 2, 0), );
    PHN(1, 1, if (nl) STAGE_A(a + 2, 1), );
    PHN(1, 2, if (nl) STAGE_B(a + 3, 0), );
    PHN(1, 3, if (nl) STAGE_B(a + 3, 1), if (nl) { VM4; } else { VM0; });
  }

  if constexpr (FUSE) {
    // ---- GLU + KAN-feature epilogue -> A3 plane-major (coalesced stores)
    float* gbuf = (float*)lds_raw;  // 16 slices x 16 rows x 128 pairs f32 = 128KB
#pragma unroll
    for (int mf = 0; mf < 8; ++mf) {
      const int s = wr * 8 + mf;
#pragma unroll
      for (int nf = 0; nf < 4; ++nf) {
#pragma unroll
        for (int rr = 0; rr < 4; ++rr) {
          float v = acc[mf][nf][rr];
          float w = __shfl_xor(v, 1, 64);
          if (!(lane & 1)) {
            const int r4 = (lane >> 4) * 4 + rr;
            const int ploc = wc * 32 + nf * 8 + ((lane & 14) >> 1);
            gbuf[s * 2048 + r4 * 128 + ploc] = v * w;
          }
        }
      }
    }
    __builtin_amdgcn_s_barrier();
    const int p2 = tid & 63;
    const int rb = tid >> 6;
    for (int k = 0; k < 32; ++k) {
      const int rr_ = rb + 8 * k;
      const int s = rr_ >> 4, rl = rr_ & 15;
      float g0 = gbuf[s * 2048 + rl * 128 + 2 * p2];
      float g1 = gbuf[s * 2048 + rl * 128 + 2 * p2 + 1];
      unsigned short h0[9], h1[9];
      kan_feat_u(g0, h0);
      kan_feat_u(g1, h1);
      uint32_t* dst = (uint32_t*)(A3out + (brow + rr_) * (size_t)K3);
      const size_t pbase = (bcol >> 2) + p2;
#pragma unroll
      for (int f = 0; f < 9; ++f)
        dst[(size_t)f * 2048 + pbase] = (uint32_t)h0[f] | ((uint32_t)h1[f] << 16);
    }
  } else {
    // plain epilogue: C/D layout col=lane&15, row=(lane>>4)*4+r
#pragma unroll
    for (int mf = 0; mf < 8; ++mf)
#pragma unroll
      for (int nf = 0; nf < 4; ++nf) {
        const size_t r0 = brow + wr * 128 + mf * 16 + (lane >> 4) * 4;
        const size_t c0 = bcol + wc * 64 + nf * 16 + (lane & 15);
        const size_t M = (size_t)gridDim.y * 256;
        CT* C = Cp + (size_t)blockIdx.z * M * (size_t)N;
#pragma unroll
        for (int rr = 0; rr < 4; ++rr) {
          float v = acc[mf][nf][rr];
          if constexpr (std::is_same<CT, float>::value)
            C[(r0 + rr) * (size_t)N + c0] = v;
          else
            C[(r0 + rr) * (size_t)N + c0] = __float2bfloat16(v);
        }
      }
  }
}

// sum nslice split-K partials (float4-vectorized)
__global__ void reduceK(const float* __restrict__ P, float* __restrict__ out,
                        size_t quarter, int nslice) {
  size_t t = (size_t)blockIdx.x * blockDim.x + threadIdx.x;
  if (t >= quarter) return;
  const float4* p = (const float4*)P;
  float4 a = p[t];
  for (int s = 1; s < nslice; ++s) {
    float4 b = p[(size_t)s * quarter + t];
    a.x += b.x; a.y += b.y; a.z += b.z; a.w += b.w;
  }
  ((float4*)out)[t] = a;
}

// ---------------------------------------------------------------------------
extern "C" void kernel_launch(void* const* d_in, const int* in_sizes, int n_in,
                              void* d_out, int out_size, void* d_ws, size_t ws_size,
                              hipStream_t stream) {
  const float* x   = (const float*)d_in[0];
  const float* bw1 = (const float*)d_in[1];
  const float* sw1 = (const float*)d_in[2];
  const float* bw2 = (const float*)d_in[3];
  const float* sw2 = (const float*)d_in[4];
  const float* bw3 = (const float*)d_in[5];
  const float* sw3 = (const float*)d_in[6];
  float* out = (float*)d_out;
  char* ws = (char*)d_ws;

  const size_t W12_B  = (size_t)8192 * K1 * 2;   // 150,994,944
  const size_t A1_B   = (size_t)NTOK * K1 * 2;   //  75,497,472
  const size_t A3F_B  = (size_t)NTOK * K3 * 2;   // 301,989,888
  const size_t A3C_B  = (size_t)CHUNK * K3 * 2;  //  75,497,472
  const size_t HF32_B = (size_t)NTOK * 8192 * 4; // 134,217,728

  const bool fused = ws_size >= W12_B + A1_B + A3F_B;  // 528,482,304
  const bool hF32  = ws_size >= W12_B + A1_B + HF32_B; // 360,710,144 (fallback)

  __hip_bfloat16* W12 = (__hip_bfloat16*)(ws);
  __hip_bfloat16* A1  = (__hip_bfloat16*)(ws + W12_B);
  __hip_bfloat16* W3  = A1;  // A1 dead after GEMM1

  size_t pairs12 = (size_t)D_FF * D_MODEL / 2;
  int blocks12 = (int)((pairs12 + 255) / 256);
  size_t pairs3 = (size_t)D_MODEL * D_FF / 2;
  int blocks3 = (int)((pairs3 + 255) / 256);
  size_t pairsA1 = (size_t)NTOK * D_MODEL / 2;

  if (fused) {
    __hip_bfloat16* A3f = (__hip_bfloat16*)(ws + W12_B + A1_B);
    float*          Par = (float*)(ws);  // reuses W12 region after GEMM1

    pack_kan_w<<<blocks12, 256, 0, stream>>>(bw1, sw1, W12, K1, 10, 2, 0, pairs12);
    pack_kan_w<<<blocks12, 256, 0, stream>>>(bw2, sw2, W12, K1, 10, 2, 1, pairs12);
    build_a1<<<(int)((pairsA1 + 255) / 256), 256, 0, stream>>>(x, A1);
    gemm256<float, true><<<dim3(8192 / 256, NTOK / 256, 1), 512, 0, stream>>>(
        A1, W12, nullptr, 8192, K1, K1, A3f);
    pack_kan_w<<<blocks3, 256, 0, stream>>>(bw3, sw3, W3, K3, 12, 1, 0, pairs3);
    gemm256<float, false><<<dim3(D_MODEL / 256, NTOK / 256, SPLITKF), 512, 0, stream>>>(
        A3f, W3, Par, D_MODEL, K3, K3 / SPLITKF, nullptr);
    size_t quarter = (size_t)NTOK * D_MODEL / 4;
    reduceK<<<(int)((quarter + 255) / 256), 256, 0, stream>>>(Par, out, quarter, SPLITKF);
  } else {
    void*           Hv  = (void*)(ws + W12_B + A1_B);
    __hip_bfloat16* A3c = (__hip_bfloat16*)(ws);        // W12 dead after GEMM1
    float*          Par = (float*)(ws + A3C_B);

    pack_kan_w<<<blocks12, 256, 0, stream>>>(bw1, sw1, W12, K1, 10, 1, 0, pairs12);
    pack_kan_w<<<blocks12, 256, 0, stream>>>(bw2, sw2, W12, K1, 10, 1, 4096, pairs12);
    build_a1<<<(int)((pairsA1 + 255) / 256), 256, 0, stream>>>(x, A1);
    if (hF32)
      gemm256<float, false><<<dim3(8192 / 256, NTOK / 256, 1), 512, 0, stream>>>(
          A1, W12, (float*)Hv, 8192, K1, K1, nullptr);
    else
      gemm256<__hip_bfloat16, false><<<dim3(8192 / 256, NTOK / 256, 1), 512, 0, stream>>>(
          A1, W12, (__hip_bfloat16*)Hv, 8192, K1, K1, nullptr);
    pack_kan_w<<<blocks3, 256, 0, stream>>>(bw3, sw3, W3, K3, 12, 1, 0, pairs3);
    for (int c = 0; c < NTOK / CHUNK; ++c) {
      size_t pairsG = (size_t)CHUNK * D_FF / 2;
      int blocksG = (int)((pairsG + 255) / 256);
      if (hF32)
        glu_a3<float><<<blocksG, 256, 0, stream>>>(
            (const float*)Hv + (size_t)c * CHUNK * 8192, A3c);
      else
        glu_a3<__hip_bfloat16><<<blocksG, 256, 0, stream>>>(
            (const __hip_bfloat16*)Hv + (size_t)c * CHUNK * 8192, A3c);
      gemm256<float, false><<<dim3(D_MODEL / 256, CHUNK / 256, SPLITK2), 512, 0, stream>>>(
          A3c, W3, Par, D_MODEL, K3, K3 / SPLITK2, nullptr);
      size_t quarter = (size_t)CHUNK * D_MODEL / 4;
      reduceK<<<(int)((quarter + 255) / 256), 256, 0, stream>>>(
          Par, out + (size_t)c * CHUNK * D_MODEL, quarter, SPLITK2);
    }
  }
}